// Round 1
// 1108.910 us; speedup vs baseline: 1.0157x; 1.0157x over previous
//
#include <hip/hip_runtime.h>

#define NN 40000      // nodes
#define NE 640000     // edges
#define DD 128        // feature dim
#define NG 64         // graphs

typedef float vf4 __attribute__((ext_vector_type(4)));
typedef unsigned short us4 __attribute__((ext_vector_type(4)));
typedef unsigned short us8 __attribute__((ext_vector_type(8)));
typedef short bf16x8 __attribute__((ext_vector_type(8)));
typedef float f32x4 __attribute__((ext_vector_type(4)));

__device__ inline unsigned short f2bf(float f) {        // round-nearest-even
    unsigned int u = __float_as_uint(f);
    return (unsigned short)((u + 0x7fffu + ((u >> 16) & 1u)) >> 16);
}
__device__ inline float bf2f(unsigned short s) {
    return __uint_as_float((unsigned int)s << 16);
}

// ---------------------------------------------------------------------------
// edge_attr fp32 -> bf16, once per launch (164 MB result fits in 256 MB L3)
// ---------------------------------------------------------------------------
__global__ __launch_bounds__(256) void cvt_k(const float* __restrict__ ea,
                                             unsigned short* __restrict__ eb)
{
    size_t i = ((size_t)blockIdx.x * 256 + threadIdx.x) * 8;  // exact cover
    vf4 a = __builtin_nontemporal_load((const vf4*)(ea + i));
    vf4 b = __builtin_nontemporal_load((const vf4*)(ea + i + 4));
    us4 o0 = {f2bf(a.x), f2bf(a.y), f2bf(a.z), f2bf(a.w)};
    us4 o1 = {f2bf(b.x), f2bf(b.y), f2bf(b.z), f2bf(b.w)};
    *(us4*)(eb + i) = o0;
    *(us4*)(eb + i + 4) = o1;
}

// ---------------------------------------------------------------------------
// Weights: fp32 [k][n] -> transposed split-bf16 [n][k] (hi + lo), once per
// launch.  8 matrices of 128x128; mat = 2*layer + {0:w1, 1:w2}.
// Split: v = bf16(v) + bf16(v - bf16(v)) keeps ~fp32 accuracy through MFMA.
// ---------------------------------------------------------------------------
__global__ __launch_bounds__(256) void wcvt_k(
    const float* __restrict__ m0, const float* __restrict__ m1,
    const float* __restrict__ m2, const float* __restrict__ m3,
    const float* __restrict__ m4, const float* __restrict__ m5,
    const float* __restrict__ m6, const float* __restrict__ m7,
    unsigned short* __restrict__ hi, unsigned short* __restrict__ lo)
{
    const float* ms[8] = {m0, m1, m2, m3, m4, m5, m6, m7};
    int mat = blockIdx.x >> 6;                       // 64 blocks per matrix
    int idx = (blockIdx.x & 63) * 256 + threadIdx.x; // 0..16383, coalesced read
    float v = ms[mat][idx];
    int k = idx >> 7, n = idx & 127;
    unsigned short h = f2bf(v);
    size_t o = ((size_t)mat << 14) + (size_t)n * DD + k;
    hi[o] = h;
    lo[o] = f2bf(v - bf2f(h));
}

// ---------------------------------------------------------------------------
// CSR build (once per launch; edge_index constant across layers)
// ---------------------------------------------------------------------------
__global__ __launch_bounds__(256) void hist_k(const int* __restrict__ dst,
                                              int* __restrict__ cnt)
{
    int e = blockIdx.x * 256 + threadIdx.x;
    if (e < NE) atomicAdd(&cnt[dst[e]], 1);
}

// 3-phase scan: local sums (40/thread) -> one 1024 ladder -> local writeout
__global__ __launch_bounds__(1024) void scan_k(const int* __restrict__ cnt,
                                               int* __restrict__ row_ptr,
                                               int* __restrict__ cursor)
{
    __shared__ int sm[1024];
    int t = threadIdx.x;
    int base = t * 40;                       // 1024*40 = 40960 >= NN
    int s = 0;
#pragma unroll 8
    for (int i = 0; i < 40; ++i) {
        int idx = base + i;
        if (idx < NN) s += cnt[idx];
    }
    sm[t] = s;
    __syncthreads();
    for (int off = 1; off < 1024; off <<= 1) {
        int x = (t >= off) ? sm[t - off] : 0;
        __syncthreads();
        sm[t] += x;
        __syncthreads();
    }
    int run = sm[t] - s;                     // exclusive prefix
#pragma unroll 8
    for (int i = 0; i < 40; ++i) {
        int idx = base + i;
        if (idx < NN) {
            row_ptr[idx] = run;
            cursor[idx] = run;
            run += cnt[idx];
        }
    }
    if (t == 1023) row_ptr[NN] = run;        // == NE
}

__global__ __launch_bounds__(256) void fill_k(const int* __restrict__ src,
                                              const int* __restrict__ dst,
                                              int* __restrict__ cursor,
                                              int2* __restrict__ elist)
{
    int e = blockIdx.x * 256 + threadIdx.x;
    if (e < NE) {
        int d = dst[e];
        int pos = atomicAdd(&cursor[d], 1);
        elist[pos] = make_int2(src[e], e);
    }
}

// ---------------------------------------------------------------------------
// Atomic-free aggregation, bf16 edge_attr, 4-edge unroll.
// agg[n] = h[n] + sum_e relu(h[src_e] + ea[eid_e])   (the +h[n] absorbs the
// GINE residual so the GEMM has a single input stream).
// ---------------------------------------------------------------------------
__device__ inline void acc1(float4& acc, const float* __restrict__ h,
                            const unsigned short* __restrict__ eb,
                            int s, int id, int lane)
{
    const float4 xv = *(const float4*)(h + (size_t)s * DD + lane * 4);
    us4 bv = *(const us4*)(eb + (size_t)id * DD + lane * 4);
    acc.x += fmaxf(xv.x + bf2f(bv.x), 0.f);
    acc.y += fmaxf(xv.y + bf2f(bv.y), 0.f);
    acc.z += fmaxf(xv.z + bf2f(bv.z), 0.f);
    acc.w += fmaxf(xv.w + bf2f(bv.w), 0.f);
}

__global__ __launch_bounds__(256) void gather_bf(
    const float* __restrict__ h, const unsigned short* __restrict__ eb,
    const int* __restrict__ row_ptr, const int2* __restrict__ elist,
    float* __restrict__ agg)
{
    int grp = blockIdx.x * 8 + (threadIdx.x >> 5);   // node id
    int lane = threadIdx.x & 31;
    if (grp >= NN) return;
    int beg = row_ptr[grp], end = row_ptr[grp + 1];

    float4 a0 = make_float4(0.f, 0.f, 0.f, 0.f);
    float4 a1 = make_float4(0.f, 0.f, 0.f, 0.f);
    float4 a2 = make_float4(0.f, 0.f, 0.f, 0.f);
    float4 a3 = make_float4(0.f, 0.f, 0.f, 0.f);
    int e = beg;
    for (; e + 4 <= end; e += 4) {
        int2 p0 = elist[e];
        int2 p1 = elist[e + 1];
        int2 p2 = elist[e + 2];
        int2 p3 = elist[e + 3];
        acc1(a0, h, eb, p0.x, p0.y, lane);
        acc1(a1, h, eb, p1.x, p1.y, lane);
        acc1(a2, h, eb, p2.x, p2.y, lane);
        acc1(a3, h, eb, p3.x, p3.y, lane);
    }
    for (; e < end; ++e) {
        int2 p0 = elist[e];
        acc1(a0, h, eb, p0.x, p0.y, lane);
    }
    const float4 sv = *(const float4*)(h + (size_t)grp * DD + lane * 4);
    float4 o;
    o.x = sv.x + (a0.x + a1.x) + (a2.x + a3.x);
    o.y = sv.y + (a0.y + a1.y) + (a2.y + a3.y);
    o.z = sv.z + (a0.z + a1.z) + (a2.z + a3.z);
    o.w = sv.w + (a0.w + a1.w) + (a2.w + a3.w);
    *(float4*)(agg + (size_t)grp * DD + lane * 4) = o;
}

// fp32 fallback (used only if ws_size can't hold the bf16 edge cache)
__device__ inline void acc1f(float4& acc, const float* __restrict__ h,
                             const float* __restrict__ ea,
                             int s, int id, int lane)
{
    const float4 xv = *(const float4*)(h + (size_t)s * DD + lane * 4);
    vf4 ev = __builtin_nontemporal_load((const vf4*)(ea + (size_t)id * DD + lane * 4));
    acc.x += fmaxf(xv.x + ev.x, 0.f);
    acc.y += fmaxf(xv.y + ev.y, 0.f);
    acc.z += fmaxf(xv.z + ev.z, 0.f);
    acc.w += fmaxf(xv.w + ev.w, 0.f);
}

__global__ __launch_bounds__(256) void gather_f32(
    const float* __restrict__ h, const float* __restrict__ ea,
    const int* __restrict__ row_ptr, const int2* __restrict__ elist,
    float* __restrict__ agg)
{
    int grp = blockIdx.x * 8 + (threadIdx.x >> 5);
    int lane = threadIdx.x & 31;
    if (grp >= NN) return;
    int beg = row_ptr[grp], end = row_ptr[grp + 1];

    float4 a0 = make_float4(0.f, 0.f, 0.f, 0.f);
    float4 a1 = make_float4(0.f, 0.f, 0.f, 0.f);
    float4 a2 = make_float4(0.f, 0.f, 0.f, 0.f);
    float4 a3 = make_float4(0.f, 0.f, 0.f, 0.f);
    int e = beg;
    for (; e + 4 <= end; e += 4) {
        int2 p0 = elist[e];
        int2 p1 = elist[e + 1];
        int2 p2 = elist[e + 2];
        int2 p3 = elist[e + 3];
        acc1f(a0, h, ea, p0.x, p0.y, lane);
        acc1f(a1, h, ea, p1.x, p1.y, lane);
        acc1f(a2, h, ea, p2.x, p2.y, lane);
        acc1f(a3, h, ea, p3.x, p3.y, lane);
    }
    for (; e < end; ++e) {
        int2 p0 = elist[e];
        acc1f(a0, h, ea, p0.x, p0.y, lane);
    }
    const float4 sv = *(const float4*)(h + (size_t)grp * DD + lane * 4);
    float4 o;
    o.x = sv.x + (a0.x + a1.x) + (a2.x + a3.x);
    o.y = sv.y + (a0.y + a1.y) + (a2.y + a3.y);
    o.z = sv.z + (a0.z + a1.z) + (a2.z + a3.z);
    o.w = sv.w + (a0.w + a1.w) + (a2.w + a3.w);
    *(float4*)(agg + (size_t)grp * DD + lane * 4) = o;
}

// ---------------------------------------------------------------------------
// Split-bf16 MFMA GEMM + bias + ReLU:  C = relu(A @ W + bias)
// M = 40000 (625 blocks x 64 rows), N = K = 128 staged whole (no K loop).
// A,W split hi/lo in LDS; 3 MFMA per (nf,ks): Ah*Wh + Ah*Wl + Al*Wh keeps
// fp32-class accuracy (err ~3e-5 rel) on the bf16 matrix pipe.
// 4 waves, wave = 16 rows x 128 cols, mfma_f32_16x16x32_bf16.
// LDS 96 KB -> 1 block/CU (memory-streaming kernel; compute is ~free).
// XOR swizzle byte^=(row&7)<<4 on write AND read: row-major K=128 bf16 is
// otherwise a 16-way bank conflict on ds_read_b128 (G4).
// In-place safe (C==A): all A reads precede the single __syncthreads().
// ---------------------------------------------------------------------------
__global__ __launch_bounds__(256) void mfma_mlp(
    const float* A,
    const unsigned short* __restrict__ Wh,   // [128 n][128 k] bf16 hi
    const unsigned short* __restrict__ Wl,   // [128 n][128 k] bf16 lo
    const float* __restrict__ bias,
    float* C)
{
    __shared__ __align__(16) char lds[96 * 1024];
    char* lAh = lds;                 // 16 KB  [64 r][128 k] bf16, swizzled
    char* lAl = lds + 16 * 1024;     // 16 KB
    char* lBh = lds + 32 * 1024;     // 32 KB  [128 n][128 k] bf16, swizzled
    char* lBl = lds + 64 * 1024;     // 32 KB

    const int tid = threadIdx.x;
    const int m0 = blockIdx.x * 64;

    // ---- stage A: fp32 -> split bf16, 64 rows x 128 (32 floats/thread)
    {
        const int row = tid >> 2;
        const int c0 = (tid & 3) * 32;
        const float* srcp = A + (size_t)(m0 + row) * DD + c0;
        const int base = row * 256 + c0 * 2;
        const int sw = (row & 7) << 4;
#pragma unroll
        for (int i = 0; i < 4; ++i) {
            float4 v0 = *(const float4*)(srcp + i * 8);
            float4 v1 = *(const float4*)(srcp + i * 8 + 4);
            float f[8] = {v0.x, v0.y, v0.z, v0.w, v1.x, v1.y, v1.z, v1.w};
            us8 hv, lv;
#pragma unroll
            for (int j = 0; j < 8; ++j) {
                unsigned short hb = f2bf(f[j]);
                hv[j] = hb;
                lv[j] = f2bf(f[j] - bf2f(hb));
            }
            const int off = (base + i * 16) ^ sw;
            *(us8*)(lAh + off) = hv;
            *(us8*)(lAl + off) = lv;
        }
    }
    // ---- stage W: bf16 linear -> LDS swizzled, 128 x 128 (hi + lo)
    {
        const int n = tid >> 1;
        const int k0 = (tid & 1) * 64;
        const unsigned short* sh = Wh + (size_t)n * DD + k0;
        const unsigned short* sl = Wl + (size_t)n * DD + k0;
        const int base = n * 256 + k0 * 2;
        const int sw = (n & 7) << 4;
#pragma unroll
        for (int i = 0; i < 8; ++i) {
            const int off = (base + i * 16) ^ sw;
            *(us8*)(lBh + off) = *(const us8*)(sh + i * 8);
            *(us8*)(lBl + off) = *(const us8*)(sl + i * 8);
        }
    }
    __syncthreads();

    // ---- MFMA: A-frag row=lane&15, k=(lane>>4)*8+j; B-frag col=lane&15,
    //      same k; C/D col=lane&15, row=(lane>>4)*4+reg  (m89-verified)
    const int lane = tid & 63;
    const int wid = tid >> 6;
    const int lr = lane & 15;
    const int kg = lane >> 4;
    const int swr = (lr & 7) << 4;

    bf16x8 ah[4], al[4];
#pragma unroll
    for (int ks = 0; ks < 4; ++ks) {
        const int off = ((wid * 16 + lr) * 256 + ks * 64 + kg * 16) ^ swr;
        ah[ks] = *(const bf16x8*)(lAh + off);
        al[ks] = *(const bf16x8*)(lAl + off);
    }
    f32x4 acc[8];
#pragma unroll
    for (int nf = 0; nf < 8; ++nf) acc[nf] = (f32x4){0.f, 0.f, 0.f, 0.f};
#pragma unroll
    for (int nf = 0; nf < 8; ++nf) {
#pragma unroll
        for (int ks = 0; ks < 4; ++ks) {
            const int off = ((nf * 16 + lr) * 256 + ks * 64 + kg * 16) ^ swr;
            bf16x8 bh = *(const bf16x8*)(lBh + off);
            bf16x8 bl = *(const bf16x8*)(lBl + off);
            acc[nf] = __builtin_amdgcn_mfma_f32_16x16x32_bf16(ah[ks], bh, acc[nf], 0, 0, 0);
            acc[nf] = __builtin_amdgcn_mfma_f32_16x16x32_bf16(ah[ks], bl, acc[nf], 0, 0, 0);
            acc[nf] = __builtin_amdgcn_mfma_f32_16x16x32_bf16(al[ks], bh, acc[nf], 0, 0, 0);
        }
    }
    // ---- epilogue: bias + relu, 4B stores (16 lanes = 64 B segments)
#pragma unroll
    for (int nf = 0; nf < 8; ++nf) {
        const int col = nf * 16 + lr;
        const float b = bias[col];
        float* cp = C + (size_t)(m0 + wid * 16 + kg * 4) * DD + col;
#pragma unroll
        for (int r = 0; r < 4; ++r)
            cp[(size_t)r * DD] = fmaxf(acc[nf][r] + b, 0.0f);
    }
}

// ---------------------------------------------------------------------------
// Global mean pool (batch sorted -> register runs, flush on graph change)
// ---------------------------------------------------------------------------
__device__ inline void pool_flush(float* __restrict__ out, int g, int lane,
                                  const float4& acc)
{
    float* o = out + (size_t)g * DD + lane * 4;
    unsafeAtomicAdd(o + 0, acc.x);
    unsafeAtomicAdd(o + 1, acc.y);
    unsafeAtomicAdd(o + 2, acc.z);
    unsafeAtomicAdd(o + 3, acc.w);
}

__global__ __launch_bounds__(256) void pool_k(
    const float* __restrict__ h, const int* __restrict__ batch,
    float* __restrict__ out, int* __restrict__ cnt)
{
    int tid = blockIdx.x * 256 + threadIdx.x;
    int grp = tid >> 5;
    int lane = tid & 31;
    int n0 = grp * 16;
    if (n0 >= NN) return;
    int nend = min(n0 + 16, NN);

    float4 acc = make_float4(0.f, 0.f, 0.f, 0.f);
    int gprev = batch[n0];
    int crun = 0;
    for (int n = n0; n < nend; ++n) {
        int g = batch[n];
        if (g != gprev) {
            pool_flush(out, gprev, lane, acc);
            if (lane == 0) atomicAdd(cnt + gprev, crun);
            acc = make_float4(0.f, 0.f, 0.f, 0.f);
            crun = 0;
            gprev = g;
        }
        float4 v = *(const float4*)(h + (size_t)n * DD + lane * 4);
        acc.x += v.x; acc.y += v.y; acc.z += v.z; acc.w += v.w;
        ++crun;
    }
    pool_flush(out, gprev, lane, acc);
    if (lane == 0) atomicAdd(cnt + gprev, crun);
}

__global__ __launch_bounds__(256) void pool_div_k(float* __restrict__ out,
                                                  const int* __restrict__ cnt)
{
    int tid = blockIdx.x * 256 + threadIdx.x;
    if (tid >= NG * DD) return;
    int g = tid / DD;
    float c = fmaxf((float)cnt[g], 1.0f);
    out[tid] = out[tid] / c;
}

// ---------------------------------------------------------------------------
extern "C" void kernel_launch(void* const* d_in, const int* in_sizes, int n_in,
                              void* d_out, int out_size, void* d_ws, size_t ws_size,
                              hipStream_t stream)
{
    const float* x     = (const float*)d_in[0];
    const float* ea    = (const float*)d_in[1];
    const int*   ei    = (const int*)d_in[2];
    const int*   batch = (const int*)d_in[3];
    const float* w1[4], * b1[4], * w2[4], * b2[4];
    for (int l = 0; l < 4; ++l) {
        w1[l] = (const float*)d_in[4 + 4 * l];
        b1[l] = (const float*)d_in[5 + 4 * l];
        w2[l] = (const float*)d_in[6 + 4 * l];
        b2[l] = (const float*)d_in[7 + 4 * l];
    }

    const int* srcp = ei;            // edge_index[0]
    const int* dstp = ei + NE;       // edge_index[1]

    char* ws = (char*)d_ws;
    const size_t hbytes = (size_t)NN * DD * sizeof(float);   // 20.48 MB
    float* agg = (float*)ws;
    float* hA  = (float*)(ws + hbytes);
    char*  p   = ws + 2 * hbytes;
    int*  cnt_node = (int*)p;           p += ((NN * 4 + 255) & ~255);
    int*  row_ptr  = (int*)p;           p += (((NN + 1) * 4 + 255) & ~255);
    int*  cursor   = (int*)p;           p += ((NN * 4 + 255) & ~255);
    int2* elist    = (int2*)p;          p += (((size_t)NE * 8 + 255) & ~255);
    int*  cntG     = (int*)p;           p += 256;
    unsigned short* wt_hi = (unsigned short*)p;  p += (size_t)8 * 16384 * 2;  // 256 KB
    unsigned short* wt_lo = (unsigned short*)p;  p += (size_t)8 * 16384 * 2;  // 256 KB
    unsigned short* ea_bf = (unsigned short*)p;
    const size_t need_bf = (size_t)(p - ws) + (size_t)NE * DD * 2;
    const bool use_bf = (ws_size >= need_bf);   // ws_size is call-invariant

    const int eblocks     = (NE + 255) / 256;   // 2500
    const int gblocks     = (NN + 7) / 8;       // 5000
    const int gemm_blocks = NN / 64;            // 625
    const int pool_blocks = ((NN / 16) * 32 + 255) / 256;

    // ---- one-time per launch: bf16 edge cache + split-bf16 weights + CSR
    if (use_bf)
        cvt_k<<<(NE * DD / 8 + 255) / 256, 256, 0, stream>>>(ea, ea_bf);
    wcvt_k<<<512, 256, 0, stream>>>(w1[0], w2[0], w1[1], w2[1],
                                    w1[2], w2[2], w1[3], w2[3], wt_hi, wt_lo);
    hipMemsetAsync(cnt_node, 0, NN * sizeof(int), stream);
    hist_k<<<eblocks, 256, 0, stream>>>(dstp, cnt_node);
    scan_k<<<1, 1024, 0, stream>>>(cnt_node, row_ptr, cursor);
    fill_k<<<eblocks, 256, 0, stream>>>(srcp, dstp, cursor, elist);

    // ---- 4 GINE layers
    const float* hcur = x;
    for (int l = 0; l < 4; ++l) {
        // agg = hcur + sum_e relu(hcur[src] + ea)   (residual fused in)
        if (use_bf)
            gather_bf<<<gblocks, 256, 0, stream>>>(hcur, ea_bf, row_ptr, elist, agg);
        else
            gather_f32<<<gblocks, 256, 0, stream>>>(hcur, ea, row_ptr, elist, agg);
        const unsigned short* h1 = wt_hi + ((size_t)(2 * l) << 14);
        const unsigned short* lo1 = wt_lo + ((size_t)(2 * l) << 14);
        const unsigned short* h2 = wt_hi + ((size_t)(2 * l + 1) << 14);
        const unsigned short* lo2 = wt_lo + ((size_t)(2 * l + 1) << 14);
        // u = relu(agg @ W1 + b1), in place over agg (block-local rows only)
        mfma_mlp<<<gemm_blocks, 256, 0, stream>>>(agg, h1, lo1, b1[l], agg);
        // hnext = relu(u @ W2 + b2)
        mfma_mlp<<<gemm_blocks, 256, 0, stream>>>(agg, h2, lo2, b2[l], hA);
        hcur = hA;
    }

    // ---- global mean pool
    hipMemsetAsync(d_out, 0, (size_t)NG * DD * sizeof(float), stream);
    hipMemsetAsync(cntG, 0, NG * sizeof(int), stream);
    pool_k<<<pool_blocks, 256, 0, stream>>>(hcur, batch, (float*)d_out, cntG);
    pool_div_k<<<(NG * DD + 255) / 256, 256, 0, stream>>>((float*)d_out, cntG);
}

// Round 2
// 1026.934 us; speedup vs baseline: 1.0968x; 1.0798x over previous
//
#include <hip/hip_runtime.h>

#define NN 40000      // nodes
#define NE 640000     // edges
#define DD 128        // feature dim
#define NG 64         // graphs

typedef float vf4 __attribute__((ext_vector_type(4)));
typedef unsigned short us4 __attribute__((ext_vector_type(4)));
typedef unsigned short us8 __attribute__((ext_vector_type(8)));
typedef short bf16x8 __attribute__((ext_vector_type(8)));
typedef float f32x4 __attribute__((ext_vector_type(4)));

__device__ inline unsigned short f2bf(float f) {        // round-nearest-even
    unsigned int u = __float_as_uint(f);
    return (unsigned short)((u + 0x7fffu + ((u >> 16) & 1u)) >> 16);
}
__device__ inline float bf2f(unsigned short s) {
    return __uint_as_float((unsigned int)s << 16);
}

// ---------------------------------------------------------------------------
// fp32 -> bf16 bulk convert (edge_attr once per launch; x once per launch).
// count must be a multiple of 2048 (NE*DD and NN*DD both are).
// ---------------------------------------------------------------------------
__global__ __launch_bounds__(256) void cvt_k(const float* __restrict__ ea,
                                             unsigned short* __restrict__ eb)
{
    size_t i = ((size_t)blockIdx.x * 256 + threadIdx.x) * 8;  // exact cover
    vf4 a = __builtin_nontemporal_load((const vf4*)(ea + i));
    vf4 b = __builtin_nontemporal_load((const vf4*)(ea + i + 4));
    us4 o0 = {f2bf(a.x), f2bf(a.y), f2bf(a.z), f2bf(a.w)};
    us4 o1 = {f2bf(b.x), f2bf(b.y), f2bf(b.z), f2bf(b.w)};
    *(us4*)(eb + i) = o0;
    *(us4*)(eb + i + 4) = o1;
}

// ---------------------------------------------------------------------------
// Weights: fp32 [k][n] -> transposed split-bf16 [n][k] (hi + lo), once per
// launch.  8 matrices of 128x128; mat = 2*layer + {0:w1, 1:w2}.
// Split: v = bf16(v) + bf16(v - bf16(v)) keeps ~fp32 accuracy through MFMA.
// ---------------------------------------------------------------------------
__global__ __launch_bounds__(256) void wcvt_k(
    const float* __restrict__ m0, const float* __restrict__ m1,
    const float* __restrict__ m2, const float* __restrict__ m3,
    const float* __restrict__ m4, const float* __restrict__ m5,
    const float* __restrict__ m6, const float* __restrict__ m7,
    unsigned short* __restrict__ hi, unsigned short* __restrict__ lo)
{
    const float* ms[8] = {m0, m1, m2, m3, m4, m5, m6, m7};
    int mat = blockIdx.x >> 6;                       // 64 blocks per matrix
    int idx = (blockIdx.x & 63) * 256 + threadIdx.x; // 0..16383, coalesced read
    float v = ms[mat][idx];
    int k = idx >> 7, n = idx & 127;
    unsigned short h = f2bf(v);
    size_t o = ((size_t)mat << 14) + (size_t)n * DD + k;
    hi[o] = h;
    lo[o] = f2bf(v - bf2f(h));
}

// ---------------------------------------------------------------------------
// CSR build (once per launch; edge_index constant across layers)
// ---------------------------------------------------------------------------
__global__ __launch_bounds__(256) void hist_k(const int* __restrict__ dst,
                                              int* __restrict__ cnt)
{
    int e = blockIdx.x * 256 + threadIdx.x;
    if (e < NE) atomicAdd(&cnt[dst[e]], 1);
}

// 3-phase scan: local sums (40/thread) -> one 1024 ladder -> local writeout
__global__ __launch_bounds__(1024) void scan_k(const int* __restrict__ cnt,
                                               int* __restrict__ row_ptr,
                                               int* __restrict__ cursor)
{
    __shared__ int sm[1024];
    int t = threadIdx.x;
    int base = t * 40;                       // 1024*40 = 40960 >= NN
    int s = 0;
#pragma unroll 8
    for (int i = 0; i < 40; ++i) {
        int idx = base + i;
        if (idx < NN) s += cnt[idx];
    }
    sm[t] = s;
    __syncthreads();
    for (int off = 1; off < 1024; off <<= 1) {
        int x = (t >= off) ? sm[t - off] : 0;
        __syncthreads();
        sm[t] += x;
        __syncthreads();
    }
    int run = sm[t] - s;                     // exclusive prefix
#pragma unroll 8
    for (int i = 0; i < 40; ++i) {
        int idx = base + i;
        if (idx < NN) {
            row_ptr[idx] = run;
            cursor[idx] = run;
            run += cnt[idx];
        }
    }
    if (t == 1023) row_ptr[NN] = run;        // == NE
}

__global__ __launch_bounds__(256) void fill_k(const int* __restrict__ src,
                                              const int* __restrict__ dst,
                                              int* __restrict__ cursor,
                                              int2* __restrict__ elist)
{
    int e = blockIdx.x * 256 + threadIdx.x;
    if (e < NE) {
        int d = dst[e];
        int pos = atomicAdd(&cursor[d], 1);
        elist[pos] = make_int2(src[e], e);
    }
}

// ---------------------------------------------------------------------------
// Atomic-free aggregation, bf16 h AND bf16 edge_attr, 4-edge unroll.
// agg[n] = h[n] + sum_e relu(h[src_e] + ea[eid_e])   (residual fused in).
// Per-edge traffic: 8 B elist + 256 B h + 256 B ea  (was 776 B with fp32 h).
// ---------------------------------------------------------------------------
__device__ inline void acc1(float4& acc, const unsigned short* __restrict__ hb,
                            const unsigned short* __restrict__ eb,
                            int s, int id, int lane)
{
    us4 xv = *(const us4*)(hb + (size_t)s * DD + lane * 4);
    us4 bv = *(const us4*)(eb + (size_t)id * DD + lane * 4);
    acc.x += fmaxf(bf2f(xv.x) + bf2f(bv.x), 0.f);
    acc.y += fmaxf(bf2f(xv.y) + bf2f(bv.y), 0.f);
    acc.z += fmaxf(bf2f(xv.z) + bf2f(bv.z), 0.f);
    acc.w += fmaxf(bf2f(xv.w) + bf2f(bv.w), 0.f);
}

__global__ __launch_bounds__(256) void gather_bf(
    const unsigned short* __restrict__ hb, const unsigned short* __restrict__ eb,
    const int* __restrict__ row_ptr, const int2* __restrict__ elist,
    float* __restrict__ agg)
{
    int grp = blockIdx.x * 8 + (threadIdx.x >> 5);   // node id
    int lane = threadIdx.x & 31;
    if (grp >= NN) return;
    int beg = row_ptr[grp], end = row_ptr[grp + 1];

    float4 a0 = make_float4(0.f, 0.f, 0.f, 0.f);
    float4 a1 = make_float4(0.f, 0.f, 0.f, 0.f);
    float4 a2 = make_float4(0.f, 0.f, 0.f, 0.f);
    float4 a3 = make_float4(0.f, 0.f, 0.f, 0.f);
    int e = beg;
    for (; e + 4 <= end; e += 4) {
        int2 p0 = elist[e];
        int2 p1 = elist[e + 1];
        int2 p2 = elist[e + 2];
        int2 p3 = elist[e + 3];
        acc1(a0, hb, eb, p0.x, p0.y, lane);
        acc1(a1, hb, eb, p1.x, p1.y, lane);
        acc1(a2, hb, eb, p2.x, p2.y, lane);
        acc1(a3, hb, eb, p3.x, p3.y, lane);
    }
    for (; e < end; ++e) {
        int2 p0 = elist[e];
        acc1(a0, hb, eb, p0.x, p0.y, lane);
    }
    us4 sv = *(const us4*)(hb + (size_t)grp * DD + lane * 4);
    float4 o;
    o.x = bf2f(sv.x) + (a0.x + a1.x) + (a2.x + a3.x);
    o.y = bf2f(sv.y) + (a0.y + a1.y) + (a2.y + a3.y);
    o.z = bf2f(sv.z) + (a0.z + a1.z) + (a2.z + a3.z);
    o.w = bf2f(sv.w) + (a0.w + a1.w) + (a2.w + a3.w);
    *(float4*)(agg + (size_t)grp * DD + lane * 4) = o;
}

// fp32 fallback (used only if ws_size can't hold the bf16 edge cache)
__device__ inline void acc1f(float4& acc, const float* __restrict__ h,
                             const float* __restrict__ ea,
                             int s, int id, int lane)
{
    const float4 xv = *(const float4*)(h + (size_t)s * DD + lane * 4);
    vf4 ev = __builtin_nontemporal_load((const vf4*)(ea + (size_t)id * DD + lane * 4));
    acc.x += fmaxf(xv.x + ev.x, 0.f);
    acc.y += fmaxf(xv.y + ev.y, 0.f);
    acc.z += fmaxf(xv.z + ev.z, 0.f);
    acc.w += fmaxf(xv.w + ev.w, 0.f);
}

__global__ __launch_bounds__(256) void gather_f32(
    const float* __restrict__ h, const float* __restrict__ ea,
    const int* __restrict__ row_ptr, const int2* __restrict__ elist,
    float* __restrict__ agg)
{
    int grp = blockIdx.x * 8 + (threadIdx.x >> 5);
    int lane = threadIdx.x & 31;
    if (grp >= NN) return;
    int beg = row_ptr[grp], end = row_ptr[grp + 1];

    float4 a0 = make_float4(0.f, 0.f, 0.f, 0.f);
    float4 a1 = make_float4(0.f, 0.f, 0.f, 0.f);
    float4 a2 = make_float4(0.f, 0.f, 0.f, 0.f);
    float4 a3 = make_float4(0.f, 0.f, 0.f, 0.f);
    int e = beg;
    for (; e + 4 <= end; e += 4) {
        int2 p0 = elist[e];
        int2 p1 = elist[e + 1];
        int2 p2 = elist[e + 2];
        int2 p3 = elist[e + 3];
        acc1f(a0, h, ea, p0.x, p0.y, lane);
        acc1f(a1, h, ea, p1.x, p1.y, lane);
        acc1f(a2, h, ea, p2.x, p2.y, lane);
        acc1f(a3, h, ea, p3.x, p3.y, lane);
    }
    for (; e < end; ++e) {
        int2 p0 = elist[e];
        acc1f(a0, h, ea, p0.x, p0.y, lane);
    }
    const float4 sv = *(const float4*)(h + (size_t)grp * DD + lane * 4);
    float4 o;
    o.x = sv.x + (a0.x + a1.x) + (a2.x + a3.x);
    o.y = sv.y + (a0.y + a1.y) + (a2.y + a3.y);
    o.z = sv.z + (a0.z + a1.z) + (a2.z + a3.z);
    o.w = sv.w + (a0.w + a1.w) + (a2.w + a3.w);
    *(float4*)(agg + (size_t)grp * DD + lane * 4) = o;
}

// ---------------------------------------------------------------------------
// Split-bf16 MFMA GEMM + bias + ReLU:  out = relu(A @ W + bias)
// M = 40000 (625 blocks x 64 rows), N = K = 128 staged whole (no K loop).
// A,W split hi/lo in LDS; 3 MFMA per (nf,ks): Ah*Wh + Ah*Wl + Al*Wh keeps
// fp32-class accuracy on the bf16 matrix pipe.
// OUT bit0: write fp32 C.  OUT bit1: write bf16 Cb (next layer's gather h).
// XOR swizzle byte^=(row&7)<<4 on write AND read (G4: row-major K=128 bf16
// is otherwise a 16-way bank conflict on ds_read_b128).
// In-place safe (C==A): all A reads precede the single __syncthreads().
// ---------------------------------------------------------------------------
template <int OUT>
__global__ __launch_bounds__(256) void mfma_mlp(
    const float* A,
    const unsigned short* __restrict__ Wh,   // [128 n][128 k] bf16 hi
    const unsigned short* __restrict__ Wl,   // [128 n][128 k] bf16 lo
    const float* __restrict__ bias,
    float* C, unsigned short* Cb)
{
    __shared__ __align__(16) char lds[96 * 1024];
    char* lAh = lds;                 // 16 KB  [64 r][128 k] bf16, swizzled
    char* lAl = lds + 16 * 1024;     // 16 KB
    char* lBh = lds + 32 * 1024;     // 32 KB  [128 n][128 k] bf16, swizzled
    char* lBl = lds + 64 * 1024;     // 32 KB

    const int tid = threadIdx.x;
    const int m0 = blockIdx.x * 64;

    // ---- stage A: fp32 -> split bf16, 64 rows x 128 (32 floats/thread)
    {
        const int row = tid >> 2;
        const int c0 = (tid & 3) * 32;
        const float* srcp = A + (size_t)(m0 + row) * DD + c0;
        const int base = row * 256 + c0 * 2;
        const int sw = (row & 7) << 4;
#pragma unroll
        for (int i = 0; i < 4; ++i) {
            float4 v0 = *(const float4*)(srcp + i * 8);
            float4 v1 = *(const float4*)(srcp + i * 8 + 4);
            float f[8] = {v0.x, v0.y, v0.z, v0.w, v1.x, v1.y, v1.z, v1.w};
            us8 hv, lv;
#pragma unroll
            for (int j = 0; j < 8; ++j) {
                unsigned short hb = f2bf(f[j]);
                hv[j] = hb;
                lv[j] = f2bf(f[j] - bf2f(hb));
            }
            const int off = (base + i * 16) ^ sw;
            *(us8*)(lAh + off) = hv;
            *(us8*)(lAl + off) = lv;
        }
    }
    // ---- stage W: bf16 linear -> LDS swizzled, 128 x 128 (hi + lo)
    {
        const int n = tid >> 1;
        const int k0 = (tid & 1) * 64;
        const unsigned short* sh = Wh + (size_t)n * DD + k0;
        const unsigned short* sl = Wl + (size_t)n * DD + k0;
        const int base = n * 256 + k0 * 2;
        const int sw = (n & 7) << 4;
#pragma unroll
        for (int i = 0; i < 8; ++i) {
            const int off = (base + i * 16) ^ sw;
            *(us8*)(lBh + off) = *(const us8*)(sh + i * 8);
            *(us8*)(lBl + off) = *(const us8*)(sl + i * 8);
        }
    }
    __syncthreads();

    // ---- MFMA: A-frag row=lane&15, k=(lane>>4)*8+j; B-frag col=lane&15,
    //      same k; C/D col=lane&15, row=(lane>>4)*4+reg  (m89-verified)
    const int lane = tid & 63;
    const int wid = tid >> 6;
    const int lr = lane & 15;
    const int kg = lane >> 4;
    const int swr = (lr & 7) << 4;

    bf16x8 ah[4], al[4];
#pragma unroll
    for (int ks = 0; ks < 4; ++ks) {
        const int off = ((wid * 16 + lr) * 256 + ks * 64 + kg * 16) ^ swr;
        ah[ks] = *(const bf16x8*)(lAh + off);
        al[ks] = *(const bf16x8*)(lAl + off);
    }
    f32x4 acc[8];
#pragma unroll
    for (int nf = 0; nf < 8; ++nf) acc[nf] = (f32x4){0.f, 0.f, 0.f, 0.f};
#pragma unroll
    for (int nf = 0; nf < 8; ++nf) {
#pragma unroll
        for (int ks = 0; ks < 4; ++ks) {
            const int off = ((nf * 16 + lr) * 256 + ks * 64 + kg * 16) ^ swr;
            bf16x8 bh = *(const bf16x8*)(lBh + off);
            bf16x8 bl = *(const bf16x8*)(lBl + off);
            acc[nf] = __builtin_amdgcn_mfma_f32_16x16x32_bf16(ah[ks], bh, acc[nf], 0, 0, 0);
            acc[nf] = __builtin_amdgcn_mfma_f32_16x16x32_bf16(ah[ks], bl, acc[nf], 0, 0, 0);
            acc[nf] = __builtin_amdgcn_mfma_f32_16x16x32_bf16(al[ks], bh, acc[nf], 0, 0, 0);
        }
    }
    // ---- epilogue: bias + relu, fp32 and/or bf16 stores
#pragma unroll
    for (int nf = 0; nf < 8; ++nf) {
        const int col = nf * 16 + lr;
        const float b = bias[col];
        float v[4];
#pragma unroll
        for (int r = 0; r < 4; ++r) v[r] = fmaxf(acc[nf][r] + b, 0.0f);
        const size_t rbase = (size_t)(m0 + wid * 16 + kg * 4) * DD + col;
        if (OUT & 1) {
#pragma unroll
            for (int r = 0; r < 4; ++r) C[rbase + (size_t)r * DD] = v[r];
        }
        if (OUT & 2) {
#pragma unroll
            for (int r = 0; r < 4; ++r) Cb[rbase + (size_t)r * DD] = f2bf(v[r]);
        }
    }
}

// ---------------------------------------------------------------------------
// Global mean pool (batch sorted -> register runs, flush on graph change)
// ---------------------------------------------------------------------------
__device__ inline void pool_flush(float* __restrict__ out, int g, int lane,
                                  const float4& acc)
{
    float* o = out + (size_t)g * DD + lane * 4;
    unsafeAtomicAdd(o + 0, acc.x);
    unsafeAtomicAdd(o + 1, acc.y);
    unsafeAtomicAdd(o + 2, acc.z);
    unsafeAtomicAdd(o + 3, acc.w);
}

__global__ __launch_bounds__(256) void pool_k(
    const float* __restrict__ h, const int* __restrict__ batch,
    float* __restrict__ out, int* __restrict__ cnt)
{
    int tid = blockIdx.x * 256 + threadIdx.x;
    int grp = tid >> 5;
    int lane = tid & 31;
    int n0 = grp * 16;
    if (n0 >= NN) return;
    int nend = min(n0 + 16, NN);

    float4 acc = make_float4(0.f, 0.f, 0.f, 0.f);
    int gprev = batch[n0];
    int crun = 0;
    for (int n = n0; n < nend; ++n) {
        int g = batch[n];
        if (g != gprev) {
            pool_flush(out, gprev, lane, acc);
            if (lane == 0) atomicAdd(cnt + gprev, crun);
            acc = make_float4(0.f, 0.f, 0.f, 0.f);
            crun = 0;
            gprev = g;
        }
        float4 v = *(const float4*)(h + (size_t)n * DD + lane * 4);
        acc.x += v.x; acc.y += v.y; acc.z += v.z; acc.w += v.w;
        ++crun;
    }
    pool_flush(out, gprev, lane, acc);
    if (lane == 0) atomicAdd(cnt + gprev, crun);
}

__global__ __launch_bounds__(256) void pool_div_k(float* __restrict__ out,
                                                  const int* __restrict__ cnt)
{
    int tid = blockIdx.x * 256 + threadIdx.x;
    if (tid >= NG * DD) return;
    int g = tid / DD;
    float c = fmaxf((float)cnt[g], 1.0f);
    out[tid] = out[tid] / c;
}

// ---------------------------------------------------------------------------
extern "C" void kernel_launch(void* const* d_in, const int* in_sizes, int n_in,
                              void* d_out, int out_size, void* d_ws, size_t ws_size,
                              hipStream_t stream)
{
    const float* x     = (const float*)d_in[0];
    const float* ea    = (const float*)d_in[1];
    const int*   ei    = (const int*)d_in[2];
    const int*   batch = (const int*)d_in[3];
    const float* w1[4], * b1[4], * w2[4], * b2[4];
    for (int l = 0; l < 4; ++l) {
        w1[l] = (const float*)d_in[4 + 4 * l];
        b1[l] = (const float*)d_in[5 + 4 * l];
        w2[l] = (const float*)d_in[6 + 4 * l];
        b2[l] = (const float*)d_in[7 + 4 * l];
    }

    const int* srcp = ei;            // edge_index[0]
    const int* dstp = ei + NE;       // edge_index[1]

    char* ws = (char*)d_ws;
    const size_t hbytes = (size_t)NN * DD * sizeof(float);   // 20.48 MB
    float* agg = (float*)ws;
    float* hA  = (float*)(ws + hbytes);
    char*  p   = ws + 2 * hbytes;
    int*  cnt_node = (int*)p;           p += ((NN * 4 + 255) & ~255);
    int*  row_ptr  = (int*)p;           p += (((NN + 1) * 4 + 255) & ~255);
    int*  cursor   = (int*)p;           p += ((NN * 4 + 255) & ~255);
    int2* elist    = (int2*)p;          p += (((size_t)NE * 8 + 255) & ~255);
    int*  cntG     = (int*)p;           p += 256;
    unsigned short* wt_hi = (unsigned short*)p;  p += (size_t)8 * 16384 * 2;  // 256 KB
    unsigned short* wt_lo = (unsigned short*)p;  p += (size_t)8 * 16384 * 2;  // 256 KB
    unsigned short* hB = (unsigned short*)p;     p += (size_t)NN * DD * 2;    // 10.24 MB
    unsigned short* ea_bf = (unsigned short*)p;
    const size_t need_bf = (size_t)(p - ws) + (size_t)NE * DD * 2;
    const bool use_bf = (ws_size >= need_bf);   // ws_size is call-invariant

    const int eblocks     = (NE + 255) / 256;   // 2500
    const int gblocks     = (NN + 7) / 8;       // 5000
    const int gemm_blocks = NN / 64;            // 625
    const int pool_blocks = ((NN / 16) * 32 + 255) / 256;

    // ---- one-time per launch: bf16 edge cache + bf16 x + split-bf16 weights
    //      + CSR by dst
    if (use_bf) {
        cvt_k<<<(size_t)NE * DD / 8 / 256, 256, 0, stream>>>(ea, ea_bf);
        cvt_k<<<(size_t)NN * DD / 8 / 256, 256, 0, stream>>>(x, hB);
    }
    wcvt_k<<<512, 256, 0, stream>>>(w1[0], w2[0], w1[1], w2[1],
                                    w1[2], w2[2], w1[3], w2[3], wt_hi, wt_lo);
    hipMemsetAsync(cnt_node, 0, NN * sizeof(int), stream);
    hist_k<<<eblocks, 256, 0, stream>>>(dstp, cnt_node);
    scan_k<<<1, 1024, 0, stream>>>(cnt_node, row_ptr, cursor);
    fill_k<<<eblocks, 256, 0, stream>>>(srcp, dstp, cursor, elist);

    // ---- 4 GINE layers
    if (use_bf) {
        for (int l = 0; l < 4; ++l) {
            // agg = h + sum_e relu(h[src] + ea)   (bf16 h, residual fused)
            gather_bf<<<gblocks, 256, 0, stream>>>(hB, ea_bf, row_ptr, elist, agg);
            const unsigned short* h1  = wt_hi + ((size_t)(2 * l) << 14);
            const unsigned short* lo1 = wt_lo + ((size_t)(2 * l) << 14);
            const unsigned short* h2  = wt_hi + ((size_t)(2 * l + 1) << 14);
            const unsigned short* lo2 = wt_lo + ((size_t)(2 * l + 1) << 14);
            // u = relu(agg @ W1 + b1), fp32, in place over agg
            mfma_mlp<1><<<gemm_blocks, 256, 0, stream>>>(agg, h1, lo1, b1[l],
                                                         agg, nullptr);
            // hnext = relu(u @ W2 + b2):
            //   layers 0-2 -> bf16 only (gather input); layer 3 -> fp32 (pool)
            if (l < 3)
                mfma_mlp<2><<<gemm_blocks, 256, 0, stream>>>(agg, h2, lo2, b2[l],
                                                             nullptr, hB);
            else
                mfma_mlp<1><<<gemm_blocks, 256, 0, stream>>>(agg, h2, lo2, b2[l],
                                                             hA, nullptr);
        }
    } else {
        const float* hcur = x;
        for (int l = 0; l < 4; ++l) {
            gather_f32<<<gblocks, 256, 0, stream>>>(hcur, ea, row_ptr, elist, agg);
            const unsigned short* h1  = wt_hi + ((size_t)(2 * l) << 14);
            const unsigned short* lo1 = wt_lo + ((size_t)(2 * l) << 14);
            const unsigned short* h2  = wt_hi + ((size_t)(2 * l + 1) << 14);
            const unsigned short* lo2 = wt_lo + ((size_t)(2 * l + 1) << 14);
            mfma_mlp<1><<<gemm_blocks, 256, 0, stream>>>(agg, h1, lo1, b1[l],
                                                         agg, nullptr);
            mfma_mlp<1><<<gemm_blocks, 256, 0, stream>>>(agg, h2, lo2, b2[l],
                                                         hA, nullptr);
            hcur = hA;
        }
    }

    // ---- global mean pool
    hipMemsetAsync(d_out, 0, (size_t)NG * DD * sizeof(float), stream);
    hipMemsetAsync(cntG, 0, NG * sizeof(int), stream);
    pool_k<<<pool_blocks, 256, 0, stream>>>(hA, batch, (float*)d_out, cntG);
    pool_div_k<<<(NG * DD + 255) / 256, 256, 0, stream>>>((float*)d_out, cntG);
}

// Round 4
// 1000.769 us; speedup vs baseline: 1.1255x; 1.0261x over previous
//
#include <hip/hip_runtime.h>

#define NN 40000      // nodes
#define NE 640000     // edges
#define DD 128        // feature dim
#define NG 64         // graphs

typedef float vf4 __attribute__((ext_vector_type(4)));
typedef unsigned short us4 __attribute__((ext_vector_type(4)));
typedef unsigned short us8 __attribute__((ext_vector_type(8)));
typedef short bf16x8 __attribute__((ext_vector_type(8)));
typedef float f32x4 __attribute__((ext_vector_type(4)));

__device__ inline unsigned short f2bf(float f) {        // round-nearest-even
    unsigned int u = __float_as_uint(f);
    return (unsigned short)((u + 0x7fffu + ((u >> 16) & 1u)) >> 16);
}
__device__ inline float bf2f(unsigned short s) {
    return __uint_as_float((unsigned int)s << 16);
}

// ---------------------------------------------------------------------------
// fp32 -> bf16 bulk convert (x once per launch).  count % 2048 == 0.
// ---------------------------------------------------------------------------
__global__ __launch_bounds__(256) void cvt_k(const float* __restrict__ ea,
                                             unsigned short* __restrict__ eb)
{
    size_t i = ((size_t)blockIdx.x * 256 + threadIdx.x) * 8;  // exact cover
    vf4 a = __builtin_nontemporal_load((const vf4*)(ea + i));
    vf4 b = __builtin_nontemporal_load((const vf4*)(ea + i + 4));
    us4 o0 = {f2bf(a.x), f2bf(a.y), f2bf(a.z), f2bf(a.w)};
    us4 o1 = {f2bf(b.x), f2bf(b.y), f2bf(b.z), f2bf(b.w)};
    *(us4*)(eb + i) = o0;
    *(us4*)(eb + i + 4) = o1;
}

// ---------------------------------------------------------------------------
// Weights: fp32 [k][n] -> transposed split-bf16 [n][k] (hi + lo), once per
// launch.  8 matrices of 128x128; mat = 2*layer + {0:w1, 1:w2}.
// ---------------------------------------------------------------------------
__global__ __launch_bounds__(256) void wcvt_k(
    const float* __restrict__ m0, const float* __restrict__ m1,
    const float* __restrict__ m2, const float* __restrict__ m3,
    const float* __restrict__ m4, const float* __restrict__ m5,
    const float* __restrict__ m6, const float* __restrict__ m7,
    unsigned short* __restrict__ hi, unsigned short* __restrict__ lo)
{
    const float* ms[8] = {m0, m1, m2, m3, m4, m5, m6, m7};
    int mat = blockIdx.x >> 6;                       // 64 blocks per matrix
    int idx = (blockIdx.x & 63) * 256 + threadIdx.x; // 0..16383, coalesced read
    float v = ms[mat][idx];
    int k = idx >> 7, n = idx & 127;
    unsigned short h = f2bf(v);
    size_t o = ((size_t)mat << 14) + (size_t)n * DD + k;
    hi[o] = h;
    lo[o] = f2bf(v - bf2f(h));
}

// ---------------------------------------------------------------------------
// CSR build (once per launch; edge_index constant across layers)
// ---------------------------------------------------------------------------
__global__ __launch_bounds__(256) void hist_k(const int* __restrict__ dst,
                                              int* __restrict__ cnt)
{
    int e = blockIdx.x * 256 + threadIdx.x;
    if (e < NE) atomicAdd(&cnt[dst[e]], 1);
}

__global__ __launch_bounds__(1024) void scan_k(const int* __restrict__ cnt,
                                               int* __restrict__ row_ptr,
                                               int* __restrict__ cursor)
{
    __shared__ int sm[1024];
    int t = threadIdx.x;
    int base = t * 40;                       // 1024*40 = 40960 >= NN
    int s = 0;
#pragma unroll 8
    for (int i = 0; i < 40; ++i) {
        int idx = base + i;
        if (idx < NN) s += cnt[idx];
    }
    sm[t] = s;
    __syncthreads();
    for (int off = 1; off < 1024; off <<= 1) {
        int x = (t >= off) ? sm[t - off] : 0;
        __syncthreads();
        sm[t] += x;
        __syncthreads();
    }
    int run = sm[t] - s;                     // exclusive prefix
#pragma unroll 8
    for (int i = 0; i < 40; ++i) {
        int idx = base + i;
        if (idx < NN) {
            row_ptr[idx] = run;
            cursor[idx] = run;
            run += cnt[idx];
        }
    }
    if (t == 1023) row_ptr[NN] = run;        // == NE
}

__global__ __launch_bounds__(256) void fill_k(const int* __restrict__ src,
                                              const int* __restrict__ dst,
                                              int* __restrict__ cursor,
                                              int2* __restrict__ elist)
{
    int e = blockIdx.x * 256 + threadIdx.x;
    if (e < NE) {
        int d = dst[e];
        int pos = atomicAdd(&cursor[d], 1);
        elist[pos] = make_int2(src[e], e);
    }
}

// ---------------------------------------------------------------------------
// Atomic-free aggregation, bf16 h + bf16 edge_attr, 4-edge unroll.
// agg[n] = h[n] + sum_e relu(h[src_e] + ea[eid_e])   (residual fused in).
// L0 variant: reads ea fp32, converts, WRITES ea_bf (each edge visited
// exactly once per layer -> full write-through cache build), accumulates
// the converted value so numerics match later layers exactly.
// ---------------------------------------------------------------------------
__device__ inline void acc1(float4& acc, const unsigned short* __restrict__ hb,
                            const unsigned short* __restrict__ eb,
                            int s, int id, int lane)
{
    us4 xv = *(const us4*)(hb + (size_t)s * DD + lane * 4);
    us4 bv = *(const us4*)(eb + (size_t)id * DD + lane * 4);
    acc.x += fmaxf(bf2f(xv.x) + bf2f(bv.x), 0.f);
    acc.y += fmaxf(bf2f(xv.y) + bf2f(bv.y), 0.f);
    acc.z += fmaxf(bf2f(xv.z) + bf2f(bv.z), 0.f);
    acc.w += fmaxf(bf2f(xv.w) + bf2f(bv.w), 0.f);
}

__device__ inline void acc1_cvt(float4& acc, const unsigned short* __restrict__ hb,
                                const float* __restrict__ ea,
                                unsigned short* __restrict__ eb,
                                int s, int id, int lane)
{
    us4 xv = *(const us4*)(hb + (size_t)s * DD + lane * 4);
    const float4 ev = *(const float4*)(ea + (size_t)id * DD + lane * 4);
    us4 bv = {f2bf(ev.x), f2bf(ev.y), f2bf(ev.z), f2bf(ev.w)};
    *(us4*)(eb + (size_t)id * DD + lane * 4) = bv;
    acc.x += fmaxf(bf2f(xv.x) + bf2f(bv.x), 0.f);
    acc.y += fmaxf(bf2f(xv.y) + bf2f(bv.y), 0.f);
    acc.z += fmaxf(bf2f(xv.z) + bf2f(bv.z), 0.f);
    acc.w += fmaxf(bf2f(xv.w) + bf2f(bv.w), 0.f);
}

template <int L0>
__global__ __launch_bounds__(256) void gather_bf(
    const unsigned short* __restrict__ hb, const unsigned short* __restrict__ eb_r,
    const float* __restrict__ ea, unsigned short* __restrict__ eb_w,
    const int* __restrict__ row_ptr, const int2* __restrict__ elist,
    float* __restrict__ agg)
{
    int grp = blockIdx.x * 8 + (threadIdx.x >> 5);   // node id
    int lane = threadIdx.x & 31;
    if (grp >= NN) return;
    int beg = row_ptr[grp], end = row_ptr[grp + 1];

    float4 a0 = make_float4(0.f, 0.f, 0.f, 0.f);
    float4 a1 = make_float4(0.f, 0.f, 0.f, 0.f);
    float4 a2 = make_float4(0.f, 0.f, 0.f, 0.f);
    float4 a3 = make_float4(0.f, 0.f, 0.f, 0.f);
    int e = beg;
    for (; e + 4 <= end; e += 4) {
        int2 p0 = elist[e];
        int2 p1 = elist[e + 1];
        int2 p2 = elist[e + 2];
        int2 p3 = elist[e + 3];
        if (L0) {
            acc1_cvt(a0, hb, ea, eb_w, p0.x, p0.y, lane);
            acc1_cvt(a1, hb, ea, eb_w, p1.x, p1.y, lane);
            acc1_cvt(a2, hb, ea, eb_w, p2.x, p2.y, lane);
            acc1_cvt(a3, hb, ea, eb_w, p3.x, p3.y, lane);
        } else {
            acc1(a0, hb, eb_r, p0.x, p0.y, lane);
            acc1(a1, hb, eb_r, p1.x, p1.y, lane);
            acc1(a2, hb, eb_r, p2.x, p2.y, lane);
            acc1(a3, hb, eb_r, p3.x, p3.y, lane);
        }
    }
    for (; e < end; ++e) {
        int2 p0 = elist[e];
        if (L0) acc1_cvt(a0, hb, ea, eb_w, p0.x, p0.y, lane);
        else    acc1(a0, hb, eb_r, p0.x, p0.y, lane);
    }
    us4 sv = *(const us4*)(hb + (size_t)grp * DD + lane * 4);
    float4 o;
    o.x = bf2f(sv.x) + (a0.x + a1.x) + (a2.x + a3.x);
    o.y = bf2f(sv.y) + (a0.y + a1.y) + (a2.y + a3.y);
    o.z = bf2f(sv.z) + (a0.z + a1.z) + (a2.z + a3.z);
    o.w = bf2f(sv.w) + (a0.w + a1.w) + (a2.w + a3.w);
    *(float4*)(agg + (size_t)grp * DD + lane * 4) = o;
}

// fp32 fallback (used only if ws_size can't hold the bf16 edge cache)
__device__ inline void acc1f(float4& acc, const float* __restrict__ h,
                             const float* __restrict__ ea,
                             int s, int id, int lane)
{
    const float4 xv = *(const float4*)(h + (size_t)s * DD + lane * 4);
    vf4 ev = __builtin_nontemporal_load((const vf4*)(ea + (size_t)id * DD + lane * 4));
    acc.x += fmaxf(xv.x + ev.x, 0.f);
    acc.y += fmaxf(xv.y + ev.y, 0.f);
    acc.z += fmaxf(xv.z + ev.z, 0.f);
    acc.w += fmaxf(xv.w + ev.w, 0.f);
}

__global__ __launch_bounds__(256) void gather_f32(
    const float* __restrict__ h, const float* __restrict__ ea,
    const int* __restrict__ row_ptr, const int2* __restrict__ elist,
    float* __restrict__ agg)
{
    int grp = blockIdx.x * 8 + (threadIdx.x >> 5);
    int lane = threadIdx.x & 31;
    if (grp >= NN) return;
    int beg = row_ptr[grp], end = row_ptr[grp + 1];

    float4 a0 = make_float4(0.f, 0.f, 0.f, 0.f);
    float4 a1 = make_float4(0.f, 0.f, 0.f, 0.f);
    float4 a2 = make_float4(0.f, 0.f, 0.f, 0.f);
    float4 a3 = make_float4(0.f, 0.f, 0.f, 0.f);
    int e = beg;
    for (; e + 4 <= end; e += 4) {
        int2 p0 = elist[e];
        int2 p1 = elist[e + 1];
        int2 p2 = elist[e + 2];
        int2 p3 = elist[e + 3];
        acc1f(a0, h, ea, p0.x, p0.y, lane);
        acc1f(a1, h, ea, p1.x, p1.y, lane);
        acc1f(a2, h, ea, p2.x, p2.y, lane);
        acc1f(a3, h, ea, p3.x, p3.y, lane);
    }
    for (; e < end; ++e) {
        int2 p0 = elist[e];
        acc1f(a0, h, ea, p0.x, p0.y, lane);
    }
    const float4 sv = *(const float4*)(h + (size_t)grp * DD + lane * 4);
    float4 o;
    o.x = sv.x + (a0.x + a1.x) + (a2.x + a3.x);
    o.y = sv.y + (a0.y + a1.y) + (a2.y + a3.y);
    o.z = sv.z + (a0.z + a1.z) + (a2.z + a3.z);
    o.w = sv.w + (a0.w + a1.w) + (a2.w + a3.w);
    *(float4*)(agg + (size_t)grp * DD + lane * 4) = o;
}

// ---------------------------------------------------------------------------
// Fused 2-layer MLP (split-bf16 MFMA):  out = relu(relu(A@W1+b1)@W2+b2)
// M = 40000 (625 blocks x 64 rows), N = K = 128 staged whole.
// Phase 1: A (fp32 global) -> split bf16 LDS; W1 hi/lo -> LDS; 96 MFMA.
// u stays ON-CHIP: split-bf16 back into the A LDS buffer; W2 restaged over
// W1; phase 2: 96 MFMA.  Saves the 40 MB/layer u round-trip + a dispatch.
// 3 MFMA per (nf,ks): Ah*Wh + Ah*Wl + Al*Wh = fp32-class accuracy.
// OUT bit0: fp32 C.  OUT bit1: bf16 Cb (next layer's gather h).
// XOR swizzle byte^=(row&7)<<4 on all LDS writes AND reads (G4).
// Barrier safety: A-frags are in registers before MFMA loop 1; the barrier
// after loop 1 drains lB reads (before W2 restage) and lA reads (before the
// u writeback).  All 256 threads reach every barrier unconditionally.
// ---------------------------------------------------------------------------
template <int OUT>
__global__ __launch_bounds__(256) void mlp_fused(
    const float* __restrict__ A,
    const unsigned short* __restrict__ W1h, const unsigned short* __restrict__ W1l,
    const float* __restrict__ b1v,
    const unsigned short* __restrict__ W2h, const unsigned short* __restrict__ W2l,
    const float* __restrict__ b2v,
    float* C, unsigned short* Cb)
{
    __shared__ __align__(16) char lds[96 * 1024];
    char* lAh = lds;                 // 16 KB  [64 r][128 k] bf16, swizzled
    char* lAl = lds + 16 * 1024;     // 16 KB
    char* lBh = lds + 32 * 1024;     // 32 KB  [128 n][128 k] bf16, swizzled
    char* lBl = lds + 64 * 1024;     // 32 KB

    const int tid = threadIdx.x;
    const int m0 = blockIdx.x * 64;

    // ---- stage A: fp32 -> split bf16, 64 rows x 128 (32 floats/thread)
    {
        const int row = tid >> 2;
        const int c0 = (tid & 3) * 32;
        const float* srcp = A + (size_t)(m0 + row) * DD + c0;
        const int base = row * 256 + c0 * 2;
        const int sw = (row & 7) << 4;
#pragma unroll
        for (int i = 0; i < 4; ++i) {
            float4 v0 = *(const float4*)(srcp + i * 8);
            float4 v1 = *(const float4*)(srcp + i * 8 + 4);
            float f[8] = {v0.x, v0.y, v0.z, v0.w, v1.x, v1.y, v1.z, v1.w};
            us8 hv, lv;
#pragma unroll
            for (int j = 0; j < 8; ++j) {
                unsigned short hb = f2bf(f[j]);
                hv[j] = hb;
                lv[j] = f2bf(f[j] - bf2f(hb));
            }
            const int off = (base + i * 16) ^ sw;
            *(us8*)(lAh + off) = hv;
            *(us8*)(lAl + off) = lv;
        }
    }
    // ---- stage W1: bf16 linear -> LDS swizzled, 128 x 128 (hi + lo)
    const int wn = tid >> 1;
    const int wk0 = (tid & 1) * 64;
    const int wbase = wn * 256 + wk0 * 2;
    const int wsw = (wn & 7) << 4;
    {
        const unsigned short* sh = W1h + (size_t)wn * DD + wk0;
        const unsigned short* sl = W1l + (size_t)wn * DD + wk0;
#pragma unroll
        for (int i = 0; i < 8; ++i) {
            const int off = (wbase + i * 16) ^ wsw;
            *(us8*)(lBh + off) = *(const us8*)(sh + i * 8);
            *(us8*)(lBl + off) = *(const us8*)(sl + i * 8);
        }
    }
    __syncthreads();

    // ---- fragment geometry (m89-verified 16x16x32 layouts)
    const int lane = tid & 63;
    const int wid = tid >> 6;
    const int lr = lane & 15;
    const int kg = lane >> 4;
    const int swr = (lr & 7) << 4;

    bf16x8 ah[4], al[4];
#pragma unroll
    for (int ks = 0; ks < 4; ++ks) {
        const int off = ((wid * 16 + lr) * 256 + ks * 64 + kg * 16) ^ swr;
        ah[ks] = *(const bf16x8*)(lAh + off);
        al[ks] = *(const bf16x8*)(lAl + off);
    }
    f32x4 acc[8];
#pragma unroll
    for (int nf = 0; nf < 8; ++nf) acc[nf] = (f32x4){0.f, 0.f, 0.f, 0.f};
#pragma unroll
    for (int nf = 0; nf < 8; ++nf) {
#pragma unroll
        for (int ks = 0; ks < 4; ++ks) {
            const int off = ((nf * 16 + lr) * 256 + ks * 64 + kg * 16) ^ swr;
            bf16x8 bh = *(const bf16x8*)(lBh + off);
            bf16x8 bl = *(const bf16x8*)(lBl + off);
            acc[nf] = __builtin_amdgcn_mfma_f32_16x16x32_bf16(ah[ks], bh, acc[nf], 0, 0, 0);
            acc[nf] = __builtin_amdgcn_mfma_f32_16x16x32_bf16(ah[ks], bl, acc[nf], 0, 0, 0);
            acc[nf] = __builtin_amdgcn_mfma_f32_16x16x32_bf16(al[ks], bh, acc[nf], 0, 0, 0);
        }
    }
    __syncthreads();   // all phase-1 LDS reads drained

    // ---- u = relu(acc + b1) -> split bf16 back into lA (swizzled)
#pragma unroll
    for (int nf = 0; nf < 8; ++nf) {
        const int col = nf * 16 + lr;
        const float b = b1v[col];
#pragma unroll
        for (int r = 0; r < 4; ++r) {
            float u = fmaxf(acc[nf][r] + b, 0.0f);
            const int lrow = wid * 16 + kg * 4 + r;
            const int off = (lrow * 256 + col * 2) ^ ((lrow & 7) << 4);
            unsigned short hb = f2bf(u);
            *(unsigned short*)(lAh + off) = hb;
            *(unsigned short*)(lAl + off) = f2bf(u - bf2f(hb));
        }
    }
    // ---- stage W2 over W1
    {
        const unsigned short* sh = W2h + (size_t)wn * DD + wk0;
        const unsigned short* sl = W2l + (size_t)wn * DD + wk0;
#pragma unroll
        for (int i = 0; i < 8; ++i) {
            const int off = (wbase + i * 16) ^ wsw;
            *(us8*)(lBh + off) = *(const us8*)(sh + i * 8);
            *(us8*)(lBl + off) = *(const us8*)(sl + i * 8);
        }
    }
    __syncthreads();

    // ---- phase 2: v = relu(u @ W2 + b2)
#pragma unroll
    for (int ks = 0; ks < 4; ++ks) {
        const int off = ((wid * 16 + lr) * 256 + ks * 64 + kg * 16) ^ swr;
        ah[ks] = *(const bf16x8*)(lAh + off);
        al[ks] = *(const bf16x8*)(lAl + off);
    }
#pragma unroll
    for (int nf = 0; nf < 8; ++nf) acc[nf] = (f32x4){0.f, 0.f, 0.f, 0.f};
#pragma unroll
    for (int nf = 0; nf < 8; ++nf) {
#pragma unroll
        for (int ks = 0; ks < 4; ++ks) {
            const int off = ((nf * 16 + lr) * 256 + ks * 64 + kg * 16) ^ swr;
            bf16x8 bh = *(const bf16x8*)(lBh + off);
            bf16x8 bl = *(const bf16x8*)(lBl + off);
            acc[nf] = __builtin_amdgcn_mfma_f32_16x16x32_bf16(ah[ks], bh, acc[nf], 0, 0, 0);
            acc[nf] = __builtin_amdgcn_mfma_f32_16x16x32_bf16(ah[ks], bl, acc[nf], 0, 0, 0);
            acc[nf] = __builtin_amdgcn_mfma_f32_16x16x32_bf16(al[ks], bh, acc[nf], 0, 0, 0);
        }
    }
    // ---- epilogue: bias + relu, fp32 and/or bf16 stores
#pragma unroll
    for (int nf = 0; nf < 8; ++nf) {
        const int col = nf * 16 + lr;
        const float b = b2v[col];
        float v[4];
#pragma unroll
        for (int r = 0; r < 4; ++r) v[r] = fmaxf(acc[nf][r] + b, 0.0f);
        const size_t rbase = (size_t)(m0 + wid * 16 + kg * 4) * DD + col;
        if (OUT & 1) {
#pragma unroll
            for (int r = 0; r < 4; ++r) C[rbase + (size_t)r * DD] = v[r];
        }
        if (OUT & 2) {
#pragma unroll
            for (int r = 0; r < 4; ++r) Cb[rbase + (size_t)r * DD] = f2bf(v[r]);
        }
    }
}

// ---------------------------------------------------------------------------
// Global mean pool (batch sorted -> register runs, flush on graph change)
// ---------------------------------------------------------------------------
__device__ inline void pool_flush(float* __restrict__ out, int g, int lane,
                                  const float4& acc)
{
    float* o = out + (size_t)g * DD + lane * 4;
    unsafeAtomicAdd(o + 0, acc.x);
    unsafeAtomicAdd(o + 1, acc.y);
    unsafeAtomicAdd(o + 2, acc.z);
    unsafeAtomicAdd(o + 3, acc.w);
}

__global__ __launch_bounds__(256) void pool_k(
    const float* __restrict__ h, const int* __restrict__ batch,
    float* __restrict__ out, int* __restrict__ cnt)
{
    int tid = blockIdx.x * 256 + threadIdx.x;
    int grp = tid >> 5;
    int lane = tid & 31;
    int n0 = grp * 16;
    if (n0 >= NN) return;
    int nend = min(n0 + 16, NN);

    float4 acc = make_float4(0.f, 0.f, 0.f, 0.f);
    int gprev = batch[n0];
    int crun = 0;
    for (int n = n0; n < nend; ++n) {
        int g = batch[n];
        if (g != gprev) {
            pool_flush(out, gprev, lane, acc);
            if (lane == 0) atomicAdd(cnt + gprev, crun);
            acc = make_float4(0.f, 0.f, 0.f, 0.f);
            crun = 0;
            gprev = g;
        }
        float4 v = *(const float4*)(h + (size_t)n * DD + lane * 4);
        acc.x += v.x; acc.y += v.y; acc.z += v.z; acc.w += v.w;
        ++crun;
    }
    pool_flush(out, gprev, lane, acc);
    if (lane == 0) atomicAdd(cnt + gprev, crun);
}

__global__ __launch_bounds__(256) void pool_div_k(float* __restrict__ out,
                                                  const int* __restrict__ cnt)
{
    int tid = blockIdx.x * 256 + threadIdx.x;
    if (tid >= NG * DD) return;
    int g = tid / DD;
    float c = fmaxf((float)cnt[g], 1.0f);
    out[tid] = out[tid] / c;
}

// ---------------------------------------------------------------------------
extern "C" void kernel_launch(void* const* d_in, const int* in_sizes, int n_in,
                              void* d_out, int out_size, void* d_ws, size_t ws_size,
                              hipStream_t stream)
{
    const float* x     = (const float*)d_in[0];
    const float* ea    = (const float*)d_in[1];
    const int*   ei    = (const int*)d_in[2];
    const int*   batch = (const int*)d_in[3];
    const float* w1[4], * b1[4], * w2[4], * b2[4];
    for (int l = 0; l < 4; ++l) {
        w1[l] = (const float*)d_in[4 + 4 * l];
        b1[l] = (const float*)d_in[5 + 4 * l];
        w2[l] = (const float*)d_in[6 + 4 * l];
        b2[l] = (const float*)d_in[7 + 4 * l];
    }

    const int* srcp = ei;            // edge_index[0]
    const int* dstp = ei + NE;       // edge_index[1]

    char* ws = (char*)d_ws;
    const size_t hbytes = (size_t)NN * DD * sizeof(float);   // 20.48 MB
    float* agg = (float*)ws;
    float* hA  = (float*)(ws + hbytes);
    char*  p   = ws + 2 * hbytes;
    int*  cnt_node = (int*)p;           p += ((NN * 4 + 255) & ~255);
    int*  row_ptr  = (int*)p;           p += (((NN + 1) * 4 + 255) & ~255);
    int*  cursor   = (int*)p;           p += ((NN * 4 + 255) & ~255);
    int2* elist    = (int2*)p;          p += (((size_t)NE * 8 + 255) & ~255);
    int*  cntG     = (int*)p;           p += 256;
    unsigned short* wt_hi = (unsigned short*)p;  p += (size_t)8 * 16384 * 2;  // 256 KB
    unsigned short* wt_lo = (unsigned short*)p;  p += (size_t)8 * 16384 * 2;  // 256 KB
    unsigned short* hB = (unsigned short*)p;     p += (size_t)NN * DD * 2;    // 10.24 MB
    unsigned short* ea_bf = (unsigned short*)p;
    const size_t need_bf = (size_t)(p - ws) + (size_t)NE * DD * 2;
    const bool use_bf = (ws_size >= need_bf);   // ws_size is call-invariant

    const int eblocks     = (NE + 255) / 256;   // 2500
    const int gblocks     = (NN + 7) / 8;       // 5000
    const int gemm_blocks = NN / 64;            // 625
    const int pool_blocks = ((NN / 16) * 32 + 255) / 256;

    // ---- one-time per launch: bf16 x + split-bf16 weights + CSR by dst
    //      (ea -> bf16 cache is built BY the layer-0 gather, write-through)
    if (use_bf)
        cvt_k<<<(size_t)NN * DD / 8 / 256, 256, 0, stream>>>(x, hB);
    wcvt_k<<<512, 256, 0, stream>>>(w1[0], w2[0], w1[1], w2[1],
                                    w1[2], w2[2], w1[3], w2[3], wt_hi, wt_lo);
    hipMemsetAsync(cnt_node, 0, NN * sizeof(int), stream);
    hist_k<<<eblocks, 256, 0, stream>>>(dstp, cnt_node);
    scan_k<<<1, 1024, 0, stream>>>(cnt_node, row_ptr, cursor);
    fill_k<<<eblocks, 256, 0, stream>>>(srcp, dstp, cursor, elist);

    // ---- 4 GINE layers (2 dispatches each: gather + fused MLP)
    if (use_bf) {
        for (int l = 0; l < 4; ++l) {
            if (l == 0)
                gather_bf<1><<<gblocks, 256, 0, stream>>>(hB, nullptr, ea, ea_bf,
                                                          row_ptr, elist, agg);
            else
                gather_bf<0><<<gblocks, 256, 0, stream>>>(hB, ea_bf, nullptr, nullptr,
                                                          row_ptr, elist, agg);
            const unsigned short* h1  = wt_hi + ((size_t)(2 * l) << 14);
            const unsigned short* lo1 = wt_lo + ((size_t)(2 * l) << 14);
            const unsigned short* h2  = wt_hi + ((size_t)(2 * l + 1) << 14);
            const unsigned short* lo2 = wt_lo + ((size_t)(2 * l + 1) << 14);
            if (l < 3)
                mlp_fused<2><<<gemm_blocks, 256, 0, stream>>>(
                    agg, h1, lo1, b1[l], h2, lo2, b2[l], nullptr, hB);
            else
                mlp_fused<1><<<gemm_blocks, 256, 0, stream>>>(
                    agg, h1, lo1, b1[l], h2, lo2, b2[l], hA, nullptr);
        }
    } else {
        const float* hcur = x;
        for (int l = 0; l < 4; ++l) {
            gather_f32<<<gblocks, 256, 0, stream>>>(hcur, ea, row_ptr, elist, agg);
            const unsigned short* h1  = wt_hi + ((size_t)(2 * l) << 14);
            const unsigned short* lo1 = wt_lo + ((size_t)(2 * l) << 14);
            const unsigned short* h2  = wt_hi + ((size_t)(2 * l + 1) << 14);
            const unsigned short* lo2 = wt_lo + ((size_t)(2 * l + 1) << 14);
            mlp_fused<1><<<gemm_blocks, 256, 0, stream>>>(
                agg, h1, lo1, b1[l], h2, lo2, b2[l], hA, nullptr);
            hcur = hA;
        }
    }

    // ---- global mean pool
    hipMemsetAsync(d_out, 0, (size_t)NG * DD * sizeof(float), stream);
    hipMemsetAsync(cntG, 0, NG * sizeof(int), stream);
    pool_k<<<pool_blocks, 256, 0, stream>>>(hA, batch, (float*)d_out, cntG);
    pool_div_k<<<(NG * DD + 255) / 256, 256, 0, stream>>>((float*)d_out, cntG);
}

// Round 5
// 884.181 us; speedup vs baseline: 1.2739x; 1.1319x over previous
//
#include <hip/hip_runtime.h>

#define NN 40000      // nodes
#define NE 640000     // edges
#define DD 128        // feature dim
#define NG 64         // graphs

typedef float vf4 __attribute__((ext_vector_type(4)));
typedef unsigned short us4 __attribute__((ext_vector_type(4)));
typedef unsigned short us8 __attribute__((ext_vector_type(8)));
typedef short bf16x8 __attribute__((ext_vector_type(8)));
typedef float f32x4 __attribute__((ext_vector_type(4)));

__device__ inline unsigned short f2bf(float f) {        // round-nearest-even
    unsigned int u = __float_as_uint(f);
    return (unsigned short)((u + 0x7fffu + ((u >> 16) & 1u)) >> 16);
}
__device__ inline float bf2f(unsigned short s) {
    return __uint_as_float((unsigned int)s << 16);
}

// ---------------------------------------------------------------------------
// Fused preamble: [0,2500) x->bf16 | [2500,3012) weight split | [3012,5512)
// dst histogram.  Three independent jobs, one dispatch -> they overlap on
// the CUs instead of serializing on the stream.
// ---------------------------------------------------------------------------
#define PRE_CVT_BLKS  2500
#define PRE_W_BLKS    512
#define PRE_H_BLKS    2500
#define PRE_BLOCKS    (PRE_CVT_BLKS + PRE_W_BLKS + PRE_H_BLKS)

template <int USE_BF>
__global__ __launch_bounds__(256) void preamble_k(
    const float* __restrict__ x, unsigned short* __restrict__ hB,
    const float* __restrict__ m0, const float* __restrict__ m1,
    const float* __restrict__ m2, const float* __restrict__ m3,
    const float* __restrict__ m4, const float* __restrict__ m5,
    const float* __restrict__ m6, const float* __restrict__ m7,
    unsigned short* __restrict__ whi, unsigned short* __restrict__ wlo,
    const int* __restrict__ dst, int* __restrict__ cnt)
{
    const int bid = blockIdx.x;
    if (bid < PRE_CVT_BLKS) {
        if (!USE_BF) return;
        size_t i = ((size_t)bid * 256 + threadIdx.x) * 8;   // exact cover
        vf4 a = __builtin_nontemporal_load((const vf4*)(x + i));
        vf4 b = __builtin_nontemporal_load((const vf4*)(x + i + 4));
        us4 o0 = {f2bf(a.x), f2bf(a.y), f2bf(a.z), f2bf(a.w)};
        us4 o1 = {f2bf(b.x), f2bf(b.y), f2bf(b.z), f2bf(b.w)};
        *(us4*)(hB + i) = o0;
        *(us4*)(hB + i + 4) = o1;
    } else if (bid < PRE_CVT_BLKS + PRE_W_BLKS) {
        const float* ms[8] = {m0, m1, m2, m3, m4, m5, m6, m7};
        int b = bid - PRE_CVT_BLKS;
        int mat = b >> 6;                        // 64 blocks per matrix
        int idx = (b & 63) * 256 + threadIdx.x;  // coalesced read
        float v = ms[mat][idx];
        int k = idx >> 7, n = idx & 127;
        unsigned short h = f2bf(v);
        size_t o = ((size_t)mat << 14) + (size_t)n * DD + k;
        whi[o] = h;
        wlo[o] = f2bf(v - bf2f(h));
    } else {
        int e = (bid - PRE_CVT_BLKS - PRE_W_BLKS) * 256 + threadIdx.x;
        if (e < NE) atomicAdd(&cnt[dst[e]], 1);
    }
}

// ---------------------------------------------------------------------------
// 3-phase scan: int4 local sums (40/thread) -> one 1024 ladder -> writeout
// ---------------------------------------------------------------------------
__global__ __launch_bounds__(1024) void scan_k(const int* __restrict__ cnt,
                                               int* __restrict__ row_ptr,
                                               int* __restrict__ cursor)
{
    __shared__ int sm[1024];
    int t = threadIdx.x;
    int base = t * 40;                       // 1024*40 = 40960 >= NN, 16B-aligned
    int4 buf[10];
    if (base + 40 <= NN) {
#pragma unroll
        for (int i = 0; i < 10; ++i) buf[i] = ((const int4*)(cnt + base))[i];
    } else {
#pragma unroll
        for (int i = 0; i < 10; ++i) {
            int idx = base + i * 4;
            int4 v = make_int4(0, 0, 0, 0);
            if (idx + 0 < NN) v.x = cnt[idx + 0];
            if (idx + 1 < NN) v.y = cnt[idx + 1];
            if (idx + 2 < NN) v.z = cnt[idx + 2];
            if (idx + 3 < NN) v.w = cnt[idx + 3];
            buf[i] = v;
        }
    }
    int s = 0;
#pragma unroll
    for (int i = 0; i < 10; ++i) s += buf[i].x + buf[i].y + buf[i].z + buf[i].w;
    sm[t] = s;
    __syncthreads();
    for (int off = 1; off < 1024; off <<= 1) {
        int x = (t >= off) ? sm[t - off] : 0;
        __syncthreads();
        sm[t] += x;
        __syncthreads();
    }
    int run = sm[t] - s;                     // exclusive prefix
#pragma unroll
    for (int i = 0; i < 10; ++i) {
        int idx = base + i * 4;
        if (idx + 0 < NN) { row_ptr[idx + 0] = run; cursor[idx + 0] = run; run += buf[i].x; }
        if (idx + 1 < NN) { row_ptr[idx + 1] = run; cursor[idx + 1] = run; run += buf[i].y; }
        if (idx + 2 < NN) { row_ptr[idx + 2] = run; cursor[idx + 2] = run; run += buf[i].z; }
        if (idx + 3 < NN) { row_ptr[idx + 3] = run; cursor[idx + 3] = run; run += buf[i].w; }
    }
    if (t == 1023) row_ptr[NN] = run;        // == NE
}

__global__ __launch_bounds__(256) void fill_k(const int* __restrict__ src,
                                              const int* __restrict__ dst,
                                              int* __restrict__ cursor,
                                              int2* __restrict__ elist)
{
    int e = blockIdx.x * 256 + threadIdx.x;
    if (e < NE) {
        int d = dst[e];
        int pos = atomicAdd(&cursor[d], 1);
        elist[pos] = make_int2(src[e], e);
    }
}

// ---------------------------------------------------------------------------
// Atomic-free aggregation, bf16 h + bf16 edge_attr, 4-edge unroll.
// agg[n] = h[n] + sum_e relu(h[src_e] + ea[eid_e])   (residual fused in).
// ea loads are NON-TEMPORAL (single use per layer) so the 164 MB ea stream
// doesn't evict the 16x-reused 10 MB hB from L2.
// L0 variant: reads ea fp32 (nt), converts, writes ea_bf (write-through
// cache build; each edge visited exactly once per layer).
// ---------------------------------------------------------------------------
__device__ inline void acc1(float4& acc, const unsigned short* __restrict__ hb,
                            const unsigned short* __restrict__ eb,
                            int s, int id, int lane)
{
    us4 xv = *(const us4*)(hb + (size_t)s * DD + lane * 4);
    us4 bv = __builtin_nontemporal_load((const us4*)(eb + (size_t)id * DD + lane * 4));
    acc.x += fmaxf(bf2f(xv.x) + bf2f(bv.x), 0.f);
    acc.y += fmaxf(bf2f(xv.y) + bf2f(bv.y), 0.f);
    acc.z += fmaxf(bf2f(xv.z) + bf2f(bv.z), 0.f);
    acc.w += fmaxf(bf2f(xv.w) + bf2f(bv.w), 0.f);
}

__device__ inline void acc1_cvt(float4& acc, const unsigned short* __restrict__ hb,
                                const float* __restrict__ ea,
                                unsigned short* __restrict__ eb,
                                int s, int id, int lane)
{
    us4 xv = *(const us4*)(hb + (size_t)s * DD + lane * 4);
    vf4 ev = __builtin_nontemporal_load((const vf4*)(ea + (size_t)id * DD + lane * 4));
    us4 bv = {f2bf(ev.x), f2bf(ev.y), f2bf(ev.z), f2bf(ev.w)};
    *(us4*)(eb + (size_t)id * DD + lane * 4) = bv;
    acc.x += fmaxf(bf2f(xv.x) + bf2f(bv.x), 0.f);
    acc.y += fmaxf(bf2f(xv.y) + bf2f(bv.y), 0.f);
    acc.z += fmaxf(bf2f(xv.z) + bf2f(bv.z), 0.f);
    acc.w += fmaxf(bf2f(xv.w) + bf2f(bv.w), 0.f);
}

template <int L0>
__global__ __launch_bounds__(256) void gather_bf(
    const unsigned short* __restrict__ hb, const unsigned short* __restrict__ eb_r,
    const float* __restrict__ ea, unsigned short* __restrict__ eb_w,
    const int* __restrict__ row_ptr, const int2* __restrict__ elist,
    float* __restrict__ agg)
{
    int grp = blockIdx.x * 8 + (threadIdx.x >> 5);   // node id
    int lane = threadIdx.x & 31;
    if (grp >= NN) return;
    int beg = row_ptr[grp], end = row_ptr[grp + 1];

    float4 a0 = make_float4(0.f, 0.f, 0.f, 0.f);
    float4 a1 = make_float4(0.f, 0.f, 0.f, 0.f);
    float4 a2 = make_float4(0.f, 0.f, 0.f, 0.f);
    float4 a3 = make_float4(0.f, 0.f, 0.f, 0.f);
    int e = beg;
    for (; e + 4 <= end; e += 4) {
        int2 p0 = elist[e];
        int2 p1 = elist[e + 1];
        int2 p2 = elist[e + 2];
        int2 p3 = elist[e + 3];
        if (L0) {
            acc1_cvt(a0, hb, ea, eb_w, p0.x, p0.y, lane);
            acc1_cvt(a1, hb, ea, eb_w, p1.x, p1.y, lane);
            acc1_cvt(a2, hb, ea, eb_w, p2.x, p2.y, lane);
            acc1_cvt(a3, hb, ea, eb_w, p3.x, p3.y, lane);
        } else {
            acc1(a0, hb, eb_r, p0.x, p0.y, lane);
            acc1(a1, hb, eb_r, p1.x, p1.y, lane);
            acc1(a2, hb, eb_r, p2.x, p2.y, lane);
            acc1(a3, hb, eb_r, p3.x, p3.y, lane);
        }
    }
    for (; e < end; ++e) {
        int2 p0 = elist[e];
        if (L0) acc1_cvt(a0, hb, ea, eb_w, p0.x, p0.y, lane);
        else    acc1(a0, hb, eb_r, p0.x, p0.y, lane);
    }
    us4 sv = *(const us4*)(hb + (size_t)grp * DD + lane * 4);
    float4 o;
    o.x = bf2f(sv.x) + (a0.x + a1.x) + (a2.x + a3.x);
    o.y = bf2f(sv.y) + (a0.y + a1.y) + (a2.y + a3.y);
    o.z = bf2f(sv.z) + (a0.z + a1.z) + (a2.z + a3.z);
    o.w = bf2f(sv.w) + (a0.w + a1.w) + (a2.w + a3.w);
    *(float4*)(agg + (size_t)grp * DD + lane * 4) = o;
}

// fp32 fallback (used only if ws_size can't hold the bf16 edge cache)
__device__ inline void acc1f(float4& acc, const float* __restrict__ h,
                             const float* __restrict__ ea,
                             int s, int id, int lane)
{
    const float4 xv = *(const float4*)(h + (size_t)s * DD + lane * 4);
    vf4 ev = __builtin_nontemporal_load((const vf4*)(ea + (size_t)id * DD + lane * 4));
    acc.x += fmaxf(xv.x + ev.x, 0.f);
    acc.y += fmaxf(xv.y + ev.y, 0.f);
    acc.z += fmaxf(xv.z + ev.z, 0.f);
    acc.w += fmaxf(xv.w + ev.w, 0.f);
}

__global__ __launch_bounds__(256) void gather_f32(
    const float* __restrict__ h, const float* __restrict__ ea,
    const int* __restrict__ row_ptr, const int2* __restrict__ elist,
    float* __restrict__ agg)
{
    int grp = blockIdx.x * 8 + (threadIdx.x >> 5);
    int lane = threadIdx.x & 31;
    if (grp >= NN) return;
    int beg = row_ptr[grp], end = row_ptr[grp + 1];

    float4 a0 = make_float4(0.f, 0.f, 0.f, 0.f);
    float4 a1 = make_float4(0.f, 0.f, 0.f, 0.f);
    float4 a2 = make_float4(0.f, 0.f, 0.f, 0.f);
    float4 a3 = make_float4(0.f, 0.f, 0.f, 0.f);
    int e = beg;
    for (; e + 4 <= end; e += 4) {
        int2 p0 = elist[e];
        int2 p1 = elist[e + 1];
        int2 p2 = elist[e + 2];
        int2 p3 = elist[e + 3];
        acc1f(a0, h, ea, p0.x, p0.y, lane);
        acc1f(a1, h, ea, p1.x, p1.y, lane);
        acc1f(a2, h, ea, p2.x, p2.y, lane);
        acc1f(a3, h, ea, p3.x, p3.y, lane);
    }
    for (; e < end; ++e) {
        int2 p0 = elist[e];
        acc1f(a0, h, ea, p0.x, p0.y, lane);
    }
    const float4 sv = *(const float4*)(h + (size_t)grp * DD + lane * 4);
    float4 o;
    o.x = sv.x + (a0.x + a1.x) + (a2.x + a3.x);
    o.y = sv.y + (a0.y + a1.y) + (a2.y + a3.y);
    o.z = sv.z + (a0.z + a1.z) + (a2.z + a3.z);
    o.w = sv.w + (a0.w + a1.w) + (a2.w + a3.w);
    *(float4*)(agg + (size_t)grp * DD + lane * 4) = o;
}

// ---------------------------------------------------------------------------
// Fused 2-layer MLP (split-bf16 MFMA):  out = relu(relu(A@W1+b1)@W2+b2)
// M = 40000 (625 blocks x 64 rows), K = 128 staged whole; B (weights) staged
// in TWO 64-col halves so LDS = 64 KB -> 2 blocks/CU (block 2's A-stage
// global loads overlap block 1's MFMA; was 96 KB -> 1 block/CU).
// u stays ON-CHIP (split-bf16 back into the A LDS buffer).  Numerics are
// identical to the 1-half version: same 3-MFMA split Ah*Wh+Ah*Wl+Al*Wh.
// OUT bit0: fp32 C.  OUT bit1: bf16 Cb (next layer's gather h).
// XOR swizzle byte^=(row&7)<<4 on all LDS writes AND reads (G4).
// Barrier ladder (7 barriers, all threads unconditional):
//   stageA+W1h0 | bar | ldA, mfma n0-3 | bar | W1h1 | bar | mfma n4-7 | bar
//   | u-wb + W2h0 | bar | ldU, mfma n0-3 | bar | W2h1 | bar | mfma n4-7
// ---------------------------------------------------------------------------
template <int OUT>
__global__ __launch_bounds__(256, 2) void mlp_fused(
    const float* __restrict__ A,
    const unsigned short* __restrict__ W1h, const unsigned short* __restrict__ W1l,
    const float* __restrict__ b1v,
    const unsigned short* __restrict__ W2h, const unsigned short* __restrict__ W2l,
    const float* __restrict__ b2v,
    float* C, unsigned short* Cb)
{
    __shared__ __align__(16) char lds[64 * 1024];
    char* lAh = lds;                 // 16 KB  [64 r][128 k] bf16, swizzled
    char* lAl = lds + 16 * 1024;     // 16 KB
    char* lBh = lds + 32 * 1024;     // 16 KB  [64 c][128 k] bf16 (half of N)
    char* lBl = lds + 48 * 1024;     // 16 KB

    const int tid = threadIdx.x;
    const int m0 = blockIdx.x * 64;

    // W staging geometry: 64 cols/half, 4 threads per col, 32 k each
    const int wc  = tid >> 2;
    const int wk0 = (tid & 3) * 32;
    const int wbase = wc * 256 + wk0 * 2;
    const int wsw = (wc & 7) << 4;
    auto stageW = [&](const unsigned short* Wh_, const unsigned short* Wl_,
                      int col0) {
        const unsigned short* sh = Wh_ + (size_t)(col0 + wc) * DD + wk0;
        const unsigned short* sl = Wl_ + (size_t)(col0 + wc) * DD + wk0;
#pragma unroll
        for (int i = 0; i < 4; ++i) {
            const int off = (wbase + i * 16) ^ wsw;
            *(us8*)(lBh + off) = *(const us8*)(sh + i * 8);
            *(us8*)(lBl + off) = *(const us8*)(sl + i * 8);
        }
    };

    // ---- stage A: fp32 -> split bf16, 64 rows x 128 (32 floats/thread)
    {
        const int row = tid >> 2;
        const int c0 = (tid & 3) * 32;
        const float* srcp = A + (size_t)(m0 + row) * DD + c0;
        const int base = row * 256 + c0 * 2;
        const int sw = (row & 7) << 4;
#pragma unroll
        for (int i = 0; i < 4; ++i) {
            float4 v0 = *(const float4*)(srcp + i * 8);
            float4 v1 = *(const float4*)(srcp + i * 8 + 4);
            float f[8] = {v0.x, v0.y, v0.z, v0.w, v1.x, v1.y, v1.z, v1.w};
            us8 hv, lv;
#pragma unroll
            for (int j = 0; j < 8; ++j) {
                unsigned short hb = f2bf(f[j]);
                hv[j] = hb;
                lv[j] = f2bf(f[j] - bf2f(hb));
            }
            const int off = (base + i * 16) ^ sw;
            *(us8*)(lAh + off) = hv;
            *(us8*)(lAl + off) = lv;
        }
    }
    stageW(W1h, W1l, 0);
    __syncthreads();

    // ---- fragment geometry (m89-verified 16x16x32 layouts)
    const int lane = tid & 63;
    const int wid = tid >> 6;
    const int lr = lane & 15;
    const int kg = lane >> 4;
    const int swr = (lr & 7) << 4;

    bf16x8 ah[4], al[4];
    auto loadA = [&]() {
#pragma unroll
        for (int ks = 0; ks < 4; ++ks) {
            const int off = ((wid * 16 + lr) * 256 + ks * 64 + kg * 16) ^ swr;
            ah[ks] = *(const bf16x8*)(lAh + off);
            al[ks] = *(const bf16x8*)(lAl + off);
        }
    };
    f32x4 acc[8];
    auto mfma_half = [&](int ab) {       // acc[ab..ab+3] over current lB half
#pragma unroll
        for (int nfl = 0; nfl < 4; ++nfl) {
#pragma unroll
            for (int ks = 0; ks < 4; ++ks) {
                const int off = ((nfl * 16 + lr) * 256 + ks * 64 + kg * 16) ^ swr;
                bf16x8 bh = *(const bf16x8*)(lBh + off);
                bf16x8 bl = *(const bf16x8*)(lBl + off);
                acc[ab + nfl] = __builtin_amdgcn_mfma_f32_16x16x32_bf16(ah[ks], bh, acc[ab + nfl], 0, 0, 0);
                acc[ab + nfl] = __builtin_amdgcn_mfma_f32_16x16x32_bf16(ah[ks], bl, acc[ab + nfl], 0, 0, 0);
                acc[ab + nfl] = __builtin_amdgcn_mfma_f32_16x16x32_bf16(al[ks], bh, acc[ab + nfl], 0, 0, 0);
            }
        }
    };

    // ---- phase 1: u = relu(A @ W1 + b1)
    loadA();
#pragma unroll
    for (int nf = 0; nf < 8; ++nf) acc[nf] = (f32x4){0.f, 0.f, 0.f, 0.f};
    mfma_half(0);
    __syncthreads();
    stageW(W1h, W1l, 64);
    __syncthreads();
    mfma_half(4);
    __syncthreads();

    // ---- u -> split bf16 back into lA (swizzled); stage W2 half 0
#pragma unroll
    for (int nf = 0; nf < 8; ++nf) {
        const int col = nf * 16 + lr;
        const float b = b1v[col];
#pragma unroll
        for (int r = 0; r < 4; ++r) {
            float u = fmaxf(acc[nf][r] + b, 0.0f);
            const int lrow = wid * 16 + kg * 4 + r;
            const int off = (lrow * 256 + col * 2) ^ ((lrow & 7) << 4);
            unsigned short hb = f2bf(u);
            *(unsigned short*)(lAh + off) = hb;
            *(unsigned short*)(lAl + off) = f2bf(u - bf2f(hb));
        }
    }
    stageW(W2h, W2l, 0);
    __syncthreads();

    // ---- phase 2: v = relu(u @ W2 + b2)
    loadA();
#pragma unroll
    for (int nf = 0; nf < 8; ++nf) acc[nf] = (f32x4){0.f, 0.f, 0.f, 0.f};
    mfma_half(0);
    __syncthreads();
    stageW(W2h, W2l, 64);
    __syncthreads();
    mfma_half(4);

    // ---- epilogue: bias + relu, fp32 and/or bf16 stores
#pragma unroll
    for (int nf = 0; nf < 8; ++nf) {
        const int col = nf * 16 + lr;
        const float b = b2v[col];
        float v[4];
#pragma unroll
        for (int r = 0; r < 4; ++r) v[r] = fmaxf(acc[nf][r] + b, 0.0f);
        const size_t rbase = (size_t)(m0 + wid * 16 + kg * 4) * DD + col;
        if (OUT & 1) {
#pragma unroll
            for (int r = 0; r < 4; ++r) C[rbase + (size_t)r * DD] = v[r];
        }
        if (OUT & 2) {
#pragma unroll
            for (int r = 0; r < 4; ++r) Cb[rbase + (size_t)r * DD] = f2bf(v[r]);
        }
    }
}

// ---------------------------------------------------------------------------
// Global mean pool (batch sorted -> register runs, flush on graph change)
// ---------------------------------------------------------------------------
__device__ inline void pool_flush(float* __restrict__ out, int g, int lane,
                                  const float4& acc)
{
    float* o = out + (size_t)g * DD + lane * 4;
    unsafeAtomicAdd(o + 0, acc.x);
    unsafeAtomicAdd(o + 1, acc.y);
    unsafeAtomicAdd(o + 2, acc.z);
    unsafeAtomicAdd(o + 3, acc.w);
}

__global__ __launch_bounds__(256) void pool_k(
    const float* __restrict__ h, const int* __restrict__ batch,
    float* __restrict__ out, int* __restrict__ cnt)
{
    int tid = blockIdx.x * 256 + threadIdx.x;
    int grp = tid >> 5;
    int lane = tid & 31;
    int n0 = grp * 16;
    if (n0 >= NN) return;
    int nend = min(n0 + 16, NN);

    float4 acc = make_float4(0.f, 0.f, 0.f, 0.f);
    int gprev = batch[n0];
    int crun = 0;
    for (int n = n0; n < nend; ++n) {
        int g = batch[n];
        if (g != gprev) {
            pool_flush(out, gprev, lane, acc);
            if (lane == 0) atomicAdd(cnt + gprev, crun);
            acc = make_float4(0.f, 0.f, 0.f, 0.f);
            crun = 0;
            gprev = g;
        }
        float4 v = *(const float4*)(h + (size_t)n * DD + lane * 4);
        acc.x += v.x; acc.y += v.y; acc.z += v.z; acc.w += v.w;
        ++crun;
    }
    pool_flush(out, gprev, lane, acc);
    if (lane == 0) atomicAdd(cnt + gprev, crun);
}

__global__ __launch_bounds__(256) void pool_div_k(float* __restrict__ out,
                                                  const int* __restrict__ cnt)
{
    int tid = blockIdx.x * 256 + threadIdx.x;
    if (tid >= NG * DD) return;
    int g = tid / DD;
    float c = fmaxf((float)cnt[g], 1.0f);
    out[tid] = out[tid] / c;
}

// ---------------------------------------------------------------------------
extern "C" void kernel_launch(void* const* d_in, const int* in_sizes, int n_in,
                              void* d_out, int out_size, void* d_ws, size_t ws_size,
                              hipStream_t stream)
{
    const float* x     = (const float*)d_in[0];
    const float* ea    = (const float*)d_in[1];
    const int*   ei    = (const int*)d_in[2];
    const int*   batch = (const int*)d_in[3];
    const float* w1[4], * b1[4], * w2[4], * b2[4];
    for (int l = 0; l < 4; ++l) {
        w1[l] = (const float*)d_in[4 + 4 * l];
        b1[l] = (const float*)d_in[5 + 4 * l];
        w2[l] = (const float*)d_in[6 + 4 * l];
        b2[l] = (const float*)d_in[7 + 4 * l];
    }

    const int* srcp = ei;            // edge_index[0]
    const int* dstp = ei + NE;       // edge_index[1]

    char* ws = (char*)d_ws;
    const size_t hbytes = (size_t)NN * DD * sizeof(float);   // 20.48 MB
    float* agg = (float*)ws;
    float* hA  = (float*)(ws + hbytes);
    char*  p   = ws + 2 * hbytes;
    int*  cnt_node = (int*)p;           p += ((NN * 4 + 255) & ~255);
    int*  row_ptr  = (int*)p;           p += (((NN + 1) * 4 + 255) & ~255);
    int*  cursor   = (int*)p;           p += ((NN * 4 + 255) & ~255);
    int2* elist    = (int2*)p;          p += (((size_t)NE * 8 + 255) & ~255);
    int*  cntG     = (int*)p;           p += 256;
    unsigned short* wt_hi = (unsigned short*)p;  p += (size_t)8 * 16384 * 2;  // 256 KB
    unsigned short* wt_lo = (unsigned short*)p;  p += (size_t)8 * 16384 * 2;  // 256 KB
    unsigned short* hB = (unsigned short*)p;     p += (size_t)NN * DD * 2;    // 10.24 MB
    unsigned short* ea_bf = (unsigned short*)p;
    const size_t need_bf = (size_t)(p - ws) + (size_t)NE * DD * 2;
    const bool use_bf = (ws_size >= need_bf);   // ws_size is call-invariant

    const int eblocks     = (NE + 255) / 256;   // 2500
    const int gblocks     = (NN + 7) / 8;       // 5000
    const int gemm_blocks = NN / 64;            // 625
    const int pool_blocks = ((NN / 16) * 32 + 255) / 256;

    // ---- one-time per launch: fused preamble (x->bf16 | weight split |
    //      dst histogram), then scan + fill.  ea->bf16 cache is built BY
    //      the layer-0 gather (write-through).
    hipMemsetAsync(cnt_node, 0, NN * sizeof(int), stream);
    if (use_bf)
        preamble_k<1><<<PRE_BLOCKS, 256, 0, stream>>>(
            x, hB, w1[0], w2[0], w1[1], w2[1], w1[2], w2[2], w1[3], w2[3],
            wt_hi, wt_lo, dstp, cnt_node);
    else
        preamble_k<0><<<PRE_BLOCKS, 256, 0, stream>>>(
            x, nullptr, w1[0], w2[0], w1[1], w2[1], w1[2], w2[2], w1[3], w2[3],
            wt_hi, wt_lo, dstp, cnt_node);
    scan_k<<<1, 1024, 0, stream>>>(cnt_node, row_ptr, cursor);
    fill_k<<<eblocks, 256, 0, stream>>>(srcp, dstp, cursor, elist);

    // ---- 4 GINE layers (2 dispatches each: gather + fused MLP)
    if (use_bf) {
        for (int l = 0; l < 4; ++l) {
            if (l == 0)
                gather_bf<1><<<gblocks, 256, 0, stream>>>(hB, nullptr, ea, ea_bf,
                                                          row_ptr, elist, agg);
            else
                gather_bf<0><<<gblocks, 256, 0, stream>>>(hB, ea_bf, nullptr, nullptr,
                                                          row_ptr, elist, agg);
            const unsigned short* h1  = wt_hi + ((size_t)(2 * l) << 14);
            const unsigned short* lo1 = wt_lo + ((size_t)(2 * l) << 14);
            const unsigned short* h2  = wt_hi + ((size_t)(2 * l + 1) << 14);
            const unsigned short* lo2 = wt_lo + ((size_t)(2 * l + 1) << 14);
            if (l < 3)
                mlp_fused<2><<<gemm_blocks, 256, 0, stream>>>(
                    agg, h1, lo1, b1[l], h2, lo2, b2[l], nullptr, hB);
            else
                mlp_fused<1><<<gemm_blocks, 256, 0, stream>>>(
                    agg, h1, lo1, b1[l], h2, lo2, b2[l], hA, nullptr);
        }
    } else {
        const float* hcur = x;
        for (int l = 0; l < 4; ++l) {
            gather_f32<<<gblocks, 256, 0, stream>>>(hcur, ea, row_ptr, elist, agg);
            const unsigned short* h1  = wt_hi + ((size_t)(2 * l) << 14);
            const unsigned short* lo1 = wt_lo + ((size_t)(2 * l) << 14);
            const unsigned short* h2  = wt_hi + ((size_t)(2 * l + 1) << 14);
            const unsigned short* lo2 = wt_lo + ((size_t)(2 * l + 1) << 14);
            mlp_fused<1><<<gemm_blocks, 256, 0, stream>>>(
                agg, h1, lo1, b1[l], h2, lo2, b2[l], hA, nullptr);
            hcur = hA;
        }
    }

    // ---- global mean pool
    hipMemsetAsync(d_out, 0, (size_t)NG * DD * sizeof(float), stream);
    hipMemsetAsync(cntG, 0, NG * sizeof(int), stream);
    pool_k<<<pool_blocks, 256, 0, stream>>>(hA, batch, (float*)d_out, cntG);
    pool_div_k<<<(NG * DD + 255) / 256, 256, 0, stream>>>((float*)d_out, cntG);
}